// Round 1
// baseline (2186.269 us; speedup 1.0000x reference)
//
#include <hip/hip_runtime.h>
#include <math.h>

#define EPS 1e-5f

__device__ inline void wave_red2(float& s1, float& s2){
    for (int off = 32; off; off >>= 1){
        s1 += __shfl_down(s1, off, 64);
        s2 += __shfl_down(s2, off, 64);
    }
}

// ---------------------------------------------------------------------------
// Generic conv1x1 (out[b,j,hw] = sum_c in[b,c,hw]*w[j,c]) with optional
// per-channel (sum, sumsq) stats accumulation. grid.z selects weight/out/stats
// slices (used for the 3 per-block involution conv1 launches in branch 1).
// Requires (B*HW) % 64 == 0 so that each wave has uniform j.
// ---------------------------------------------------------------------------
__global__ void conv1x1_k(const float* __restrict__ in, const float* __restrict__ w,
                          float* __restrict__ out, float* __restrict__ stats,
                          int Cin, int Cout, int HW, int B,
                          int wStrideZ, int outStrideZ, int statsStrideZ)
{
    const float* wz = w + (size_t)blockIdx.z * wStrideZ;
    float* oz = out + (size_t)blockIdx.z * outStrideZ;
    float* sz = stats ? stats + (size_t)blockIdx.z * statsStrideZ : nullptr;
    int npos = B * HW;
    int total = Cout * npos;
    int item = blockIdx.x * blockDim.x + threadIdx.x;
    if (item >= total) return;
    int j = item / npos;
    int pos = item - j * npos;
    int b = pos / HW, hw = pos - b * HW;
    const float* ip = in + (size_t)b * Cin * HW + hw;
    const float* wr = wz + (size_t)j * Cin;
    float acc = 0.f;
    for (int c = 0; c < Cin; ++c) acc += ip[(size_t)c * HW] * wr[c];
    oz[(size_t)b * Cout * HW + (size_t)j * HW + hw] = acc;
    if (sz){
        float s1 = acc, s2 = acc * acc;
        wave_red2(s1, s2);
        if ((threadIdx.x & 63) == 0){
            atomicAdd(&sz[j], s1);
            atomicAdd(&sz[Cout + j], s2);
        }
    }
}

// ---------------------------------------------------------------------------
// Branch-1 involution (C=30, Ct=15, groups=2, H=W=15). One thread per
// (group, position): applies BN+ReLU to t, computes k*k dynamic weights,
// then 15 channel outputs via the unfold window; accumulates o stats.
// ---------------------------------------------------------------------------
template<int K>
__global__ void invol_b1(const float* __restrict__ in,    // [B,30,225] patches source
                         const float* __restrict__ t_raw, // [B,15,225]
                         const float* __restrict__ tstats,// [30]: sum[15], sumsq[15]
                         const float* __restrict__ tg, const float* __restrict__ tb,
                         const float* __restrict__ w2,    // [2*K*K, 15]
                         float* __restrict__ o_raw, float* __restrict__ ostats)
{
    constexpr int KK = K * K, P = (K - 1) / 2;
    __shared__ float w2s[2 * KK * 15];
    __shared__ float tsc[16], tsh[16];
    const float invN = 1.f / 14400.f;
    for (int i = threadIdx.x; i < 2 * KK * 15; i += 256) w2s[i] = w2[i];
    if (threadIdx.x < 15){
        int j = threadIdx.x;
        float mean = tstats[j] * invN;
        float var = tstats[15 + j] * invN - mean * mean;
        float s = tg[j] * rsqrtf(var + EPS);
        tsc[j] = s; tsh[j] = tb[j] - mean * s;
    }
    __syncthreads();
    int item = blockIdx.x * 256 + threadIdx.x;
    if (item >= 2 * 14400) return;
    int g = item / 14400;
    int pos = item - g * 14400;
    int b = pos / 225, hw = pos - b * 225;
    int h = hw / 15, w = hw - h * 15;
    float wk[KK];
    #pragma unroll
    for (int kk = 0; kk < KK; ++kk) wk[kk] = 0.f;
    const float* trp = t_raw + (size_t)b * 15 * 225 + hw;
    for (int j = 0; j < 15; ++j){
        float t = trp[j * 225] * tsc[j] + tsh[j];
        t = t > 0.f ? t : 0.f;
        const float* wr = &w2s[g * KK * 15 + j];
        #pragma unroll
        for (int kk = 0; kk < KK; ++kk) wk[kk] += t * wr[kk * 15];
    }
    const float* inb = in + (size_t)b * 30 * 225;
    for (int cc = 0; cc < 15; ++cc){
        int c = g * 15 + cc;
        const float* inc = inb + c * 225;
        float acc = 0.f;
        #pragma unroll
        for (int ki = 0; ki < K; ++ki){
            int hh = h + ki - P;
            if (hh < 0 || hh >= 15) continue;
            #pragma unroll
            for (int kj = 0; kj < K; ++kj){
                int ww = w + kj - P;
                if (ww < 0 || ww >= 15) continue;
                acc += wk[ki * K + kj] * inc[hh * 15 + ww];
            }
        }
        o_raw[(size_t)b * 30 * 225 + c * 225 + hw] = acc;
        float s1 = acc, s2 = acc * acc;
        wave_red2(s1, s2);
        if ((threadIdx.x & 63) == 0){
            atomicAdd(&ostats[c], s1);
            atomicAdd(&ostats[30 + c], s2);
        }
    }
}

// ---------------------------------------------------------------------------
// Branch-1 block end: out_new[b,c,hw] = sum_{q<90} relu(bn(o_ii[cc]))*conv[c,q]
//                                      + out_old[b,c,hw]
// ---------------------------------------------------------------------------
__global__ void blockend(const float* __restrict__ o0, const float* __restrict__ o1,
                         const float* __restrict__ o2,
                         const float* __restrict__ s0, const float* __restrict__ s1,
                         const float* __restrict__ s2,
                         const float* __restrict__ g, const float* __restrict__ bb, // [3][30]
                         const float* __restrict__ conv,                            // [30][90]
                         const float* __restrict__ oldout, float* __restrict__ newout)
{
    __shared__ float sc[90], sh[90];
    int tid = threadIdx.x;
    if (tid < 90){
        int ii = tid / 30, cc = tid - ii * 30;
        const float* st = ii == 0 ? s0 : (ii == 1 ? s1 : s2);
        const float invN = 1.f / 14400.f;
        float mean = st[cc] * invN;
        float var = st[30 + cc] * invN - mean * mean;
        float s = g[tid] * rsqrtf(var + EPS);
        sc[tid] = s; sh[tid] = bb[tid] - mean * s;
    }
    __syncthreads();
    int item = blockIdx.x * 256 + tid;
    if (item >= 432000) return;
    int c = item / 14400, pos = item - c * 14400;
    int b = pos / 225, hw = pos - b * 225;
    float acc = oldout[(size_t)b * 30 * 225 + c * 225 + hw];
    const float* cr = conv + c * 90;
    const float* bases[3] = {o0, o1, o2};
    #pragma unroll
    for (int ii = 0; ii < 3; ++ii){
        const float* op = bases[ii] + (size_t)b * 30 * 225 + hw;
        for (int cc = 0; cc < 30; ++cc){
            float v = op[cc * 225] * sc[ii * 30 + cc] + sh[ii * 30 + cc];
            v = v > 0.f ? v : 0.f;
            acc += v * cr[ii * 30 + cc];
        }
    }
    newout[(size_t)b * 30 * 225 + c * 225 + hw] = acc;
}

// ---------------------------------------------------------------------------
// Branch-2 loc involution: groups == C == 204, Cg = 1, k = 3, Ct = 102.
// One thread per (channel, position); each channel has its own 9 wk rows.
// ---------------------------------------------------------------------------
__global__ void invol_loc(const float* __restrict__ y, const float* __restrict__ t_raw,
                          const float* __restrict__ tstats, const float* __restrict__ tg,
                          const float* __restrict__ tb,
                          const float* __restrict__ w2, // [1836,102]
                          float* __restrict__ out)
{
    __shared__ float tsc[102], tsh[102];
    const float invN = 1.f / 576.f;
    for (int j = threadIdx.x; j < 102; j += 256){
        float mean = tstats[j] * invN;
        float var = tstats[102 + j] * invN - mean * mean;
        float s = tg[j] * rsqrtf(var + EPS);
        tsc[j] = s; tsh[j] = tb[j] - mean * s;
    }
    __syncthreads();
    int item = blockIdx.x * 256 + threadIdx.x;
    if (item >= 204 * 576) return;
    int c = item / 576, pos = item - c * 576;
    int b = pos / 9, hw = pos - b * 9;
    int h = hw / 3, w = hw - h * 3;
    float wk[9];
    #pragma unroll
    for (int kk = 0; kk < 9; ++kk) wk[kk] = 0.f;
    const float* trp = t_raw + (size_t)b * 102 * 9 + hw;
    const float* wr = w2 + (size_t)c * 9 * 102;
    for (int j = 0; j < 102; ++j){
        float t = trp[j * 9] * tsc[j] + tsh[j];
        t = t > 0.f ? t : 0.f;
        #pragma unroll
        for (int kk = 0; kk < 9; ++kk) wk[kk] += t * wr[kk * 102 + j];
    }
    float val = 0.f;
    const float* pb = y + (size_t)b * 204 * 9 + c * 9;
    #pragma unroll
    for (int ki = 0; ki < 3; ++ki){
        int hh = h + ki - 1; if (hh < 0 || hh > 2) continue;
        #pragma unroll
        for (int kj = 0; kj < 3; ++kj){
            int ww = w + kj - 1; if (ww < 0 || ww > 2) continue;
            val += wk[ki * 3 + kj] * pb[hh * 3 + ww];
        }
    }
    out[(size_t)b * 204 * 9 + c * 9 + hw] = val;
}

// ---------------------------------------------------------------------------
// Branch-2 groups=1 involution (k=3). Threads chunked over channels (8/thread,
// wk recomputed per chunk -- cheap). Epilogue: plain write + stats, or
// crossmul: out = ymul * (locadd + val)  (no stats).
// ---------------------------------------------------------------------------
__global__ void invol_g1(const float* __restrict__ pin, const float* __restrict__ t_raw,
                         const float* __restrict__ tstats, const float* __restrict__ tg,
                         const float* __restrict__ tb,
                         const float* __restrict__ w2, float* __restrict__ out,
                         float* __restrict__ ostats, int C, int Ct,
                         const float* __restrict__ ymul, const float* __restrict__ locadd)
{
    __shared__ float w2s[9 * 102];
    __shared__ float tsc[102], tsh[102];
    const float invN = 1.f / 576.f;
    for (int i = threadIdx.x; i < 9 * Ct; i += 256) w2s[i] = w2[i];
    for (int j = threadIdx.x; j < Ct; j += 256){
        float mean = tstats[j] * invN;
        float var = tstats[Ct + j] * invN - mean * mean;
        float s = tg[j] * rsqrtf(var + EPS);
        tsc[j] = s; tsh[j] = tb[j] - mean * s;
    }
    __syncthreads();
    int nchunk = (C + 7) >> 3;
    int item = blockIdx.x * 256 + threadIdx.x;
    if (item >= nchunk * 576) return;
    int chunk = item / 576, pos = item - chunk * 576;
    int b = pos / 9, hw = pos - b * 9;
    int h = hw / 3, w = hw - h * 3;
    float wk[9];
    #pragma unroll
    for (int kk = 0; kk < 9; ++kk) wk[kk] = 0.f;
    const float* trp = t_raw + (size_t)b * Ct * 9 + hw;
    for (int j = 0; j < Ct; ++j){
        float t = trp[j * 9] * tsc[j] + tsh[j];
        t = t > 0.f ? t : 0.f;
        #pragma unroll
        for (int kk = 0; kk < 9; ++kk) wk[kk] += t * w2s[kk * Ct + j];
    }
    int c0 = chunk * 8, c1 = min(C, c0 + 8);
    const float* pb = pin + (size_t)b * C * 9;
    for (int c = c0; c < c1; ++c){
        float val = 0.f;
        #pragma unroll
        for (int ki = 0; ki < 3; ++ki){
            int hh = h + ki - 1; if (hh < 0 || hh > 2) continue;
            #pragma unroll
            for (int kj = 0; kj < 3; ++kj){
                int ww = w + kj - 1; if (ww < 0 || ww > 2) continue;
                val += wk[ki * 3 + kj] * pb[c * 9 + hh * 3 + ww];
            }
        }
        size_t oi = (size_t)b * C * 9 + c * 9 + hw;
        if (ymul){
            out[oi] = ymul[oi] * (locadd[oi] + val);
        } else {
            out[oi] = val;
            float s1 = val, s2 = val * val;
            wave_red2(s1, s2);
            if ((threadIdx.x & 63) == 0){
                atomicAdd(&ostats[c], s1);
                atomicAdd(&ostats[C + c], s2);
            }
        }
    }
}

// ---------------------------------------------------------------------------
// Elementwise: out = relu(bn(in)) [+ res]
// ---------------------------------------------------------------------------
__global__ void bn_relu_add(const float* __restrict__ in, const float* __restrict__ stats,
                            const float* __restrict__ g, const float* __restrict__ bta,
                            const float* __restrict__ res, float* __restrict__ out,
                            int C, int HW, int total, float invN)
{
    int i = blockIdx.x * 256 + threadIdx.x;
    if (i >= total) return;
    int c = (i / HW) % C;
    float mean = stats[c] * invN;
    float var = stats[C + c] * invN - mean * mean;
    float sc = g[c] * rsqrtf(var + EPS);
    float v = (in[i] - mean) * sc + bta[c];
    v = v > 0.f ? v : 0.f;
    if (res) v += res[i];
    out[i] = v;
}

// ---------------------------------------------------------------------------
// GlobalCovPooling: one workgroup per batch element, everything in LDS.
// Faithful to the reference incl. ELEMENTWISE Y-update in Newton-Schulz.
// ---------------------------------------------------------------------------
__global__ void covpool(const float* __restrict__ in, float* __restrict__ feat, int C, int N)
{
    __shared__ float X[6750];                  // max 225*30
    __shared__ float Ybuf[900], Mbuf[900], Zbuf[900], Z2buf[900];
    __shared__ float mu[32];
    __shared__ float scal[2];
    int b = blockIdx.x, tid = threadIdx.x;
    const float* ib = in + (size_t)b * C * N;
    for (int i = tid; i < N * C; i += 256){
        int n = i / C, c = i - n * C;
        X[i] = ib[(size_t)c * N + n];
    }
    __syncthreads();
    if (tid < C){
        float s = 0.f;
        for (int n = 0; n < N; ++n) s += X[n * C + tid];
        mu[tid] = s / N;
    }
    __syncthreads();
    int CC = C * C;
    for (int i = tid; i < CC; i += 256){
        int c = i / C, d = i - c * C;
        float s = 0.f;
        for (int n = 0; n < N; ++n) s += X[n * C + c] * X[n * C + d];
        Ybuf[i] = s / N - mu[c] * mu[d];       // sigma
    }
    __syncthreads();
    if (tid == 0){
        float tr = 0.f;
        for (int c = 0; c < C; ++c) tr += Ybuf[c * C + c];
        scal[0] = 1.f / tr;
    }
    __syncthreads();
    for (int i = tid; i < CC; i += 256){
        int c = i / C, d = i - c * C;
        Ybuf[i] *= scal[0];
        Zbuf[i] = (c == d) ? 1.f : 0.f;
    }
    __syncthreads();
    float* zs = Zbuf; float* zd = Z2buf;
    for (int it = 0; it < 6; ++it){
        for (int i = tid; i < CC; i += 256){
            int c = i / C, d = i - c * C;
            float s = 0.f;
            for (int e = 0; e < C; ++e) s += zs[c * C + e] * Ybuf[e * C + d];
            Mbuf[i] = ((c == d) ? 3.f : 0.f) - s;
        }
        __syncthreads();
        for (int i = tid; i < CC; i += 256){
            int c = i / C, d = i - c * C;
            float s = 0.f;
            for (int e = 0; e < C; ++e) s += Mbuf[c * C + e] * zs[e * C + d];
            zd[i] = 0.5f * s;
        }
        for (int i = tid; i < CC; i += 256) Ybuf[i] *= 0.5f * Mbuf[i];   // elementwise, as in source
        __syncthreads();
        float* t = zs; zs = zd; zd = t;
    }
    if (tid == 0){
        float tr = 0.f;
        for (int c = 0; c < C; ++c) tr += Ybuf[c * C + c];
        scal[1] = sqrtf(tr);
    }
    __syncthreads();
    if (tid < C){
        float s = 0.f;
        for (int c = 0; c < C; ++c) s += Ybuf[c * C + tid];
        feat[(size_t)b * C + tid] = scal[1] * s / C;
    }
}

// ---------------------------------------------------------------------------
// Head: concat feats, BN over batch, ReLU, linear, softmax. Single workgroup.
// ---------------------------------------------------------------------------
__global__ void head_k(const float* __restrict__ feat1, const float* __restrict__ feat2,
                       const float* __restrict__ hg, const float* __restrict__ hb,
                       const float* __restrict__ lw, const float* __restrict__ lb,
                       float* __restrict__ out)
{
    __shared__ float f[46 * 64];
    int tid = threadIdx.x;
    for (int i = tid; i < 46 * 64; i += 256){
        int ch = i / 64, b = i - ch * 64;
        f[i] = ch < 30 ? feat1[b * 30 + ch] : feat2[b * 16 + (ch - 30)];
    }
    __syncthreads();
    if (tid < 46){
        float s = 0.f, s2 = 0.f;
        for (int b = 0; b < 64; ++b){ float v = f[tid * 64 + b]; s += v; s2 += v * v; }
        float mean = s / 64.f, var = s2 / 64.f - mean * mean;
        float sc = hg[tid] * rsqrtf(var + EPS), sh = hb[tid] - mean * sc;
        for (int b = 0; b < 64; ++b){
            float v = f[tid * 64 + b] * sc + sh;
            f[tid * 64 + b] = v > 0.f ? v : 0.f;
        }
    }
    __syncthreads();
    if (tid < 64){
        int b = tid;
        float l[16];
        float m = -1e30f;
        for (int o = 0; o < 16; ++o){
            float a = lb[o];
            for (int ch = 0; ch < 46; ++ch) a += f[ch * 64 + b] * lw[o * 46 + ch];
            l[o] = a; m = fmaxf(m, a);
        }
        float se = 0.f;
        for (int o = 0; o < 16; ++o){ l[o] = expf(l[o] - m); se += l[o]; }
        float inv = 1.f / se;
        for (int o = 0; o < 16; ++o) out[b * 16 + o] = l[o] * inv;
    }
}

extern "C" void kernel_launch(void* const* d_in, const int* in_sizes, int n_in,
                              void* d_out, int out_size, void* d_ws, size_t ws_size,
                              hipStream_t stream)
{
    (void)in_sizes; (void)n_in; (void)out_size; (void)ws_size;
    const float* x        = (const float*)d_in[0];
    const float* y        = (const float*)d_in[1];
    const float* blk_w1   = (const float*)d_in[2];
    const float* blk_ig   = (const float*)d_in[3];
    const float* blk_ib   = (const float*)d_in[4];
    const float* blk_w2_5 = (const float*)d_in[5];
    const float* blk_w2_7 = (const float*)d_in[6];
    const float* blk_w2_9 = (const float*)d_in[7];
    const float* blk_g    = (const float*)d_in[8];
    const float* blk_b    = (const float*)d_in[9];
    const float* blk_conv = (const float*)d_in[10];
    const float* loc_w1 = (const float*)d_in[11];
    const float* loc_g  = (const float*)d_in[12];
    const float* loc_b  = (const float*)d_in[13];
    const float* loc_w2 = (const float*)d_in[14];
    const float* glb_w1 = (const float*)d_in[15];
    const float* glb_g  = (const float*)d_in[16];
    const float* glb_b  = (const float*)d_in[17];
    const float* glb_w2 = (const float*)d_in[18];
    const float* c3_w1 = (const float*)d_in[19];
    const float* c3_g  = (const float*)d_in[20];
    const float* c3_b  = (const float*)d_in[21];
    const float* c3_w2 = (const float*)d_in[22];
    const float* c4_w1 = (const float*)d_in[23];
    const float* c4_g  = (const float*)d_in[24];
    const float* c4_b  = (const float*)d_in[25];
    const float* c4_w2 = (const float*)d_in[26];
    const float* c5_w1 = (const float*)d_in[27];
    const float* c5_g  = (const float*)d_in[28];
    const float* c5_b  = (const float*)d_in[29];
    const float* c5_w2 = (const float*)d_in[30];
    const float* p1 = (const float*)d_in[31];
    const float* p2 = (const float*)d_in[32];
    const float* p3 = (const float*)d_in[33];
    const float* bn1g = (const float*)d_in[34];
    const float* bn1b = (const float*)d_in[35];
    const float* bn2g = (const float*)d_in[36];
    const float* bn2b = (const float*)d_in[37];
    const float* bn3g = (const float*)d_in[38];
    const float* bn3b = (const float*)d_in[39];
    const float* hg = (const float*)d_in[40];
    const float* hb = (const float*)d_in[41];
    const float* lw = (const float*)d_in[42];
    const float* lb = (const float*)d_in[43];

    float* ws = (float*)d_ws;
    size_t off = 0;
    auto alloc = [&](size_t n){ float* p = ws + off; off += n; return p; };
    float* bufA    = alloc(432000);
    float* bufB    = alloc(432000);
    float* scratch = alloc(1944000);   // branch1 t_raw(3)+o_raw(3); branch2 aliases this
    float* feat1   = alloc(64 * 30);
    float* feat2   = alloc(64 * 16);
    float* stats   = alloc(2288);

    float* t_raw = scratch;            // 3 x 216000
    float* o_raw = scratch + 648000;   // 3 x 432000

    hipMemsetAsync(stats, 0, 2288 * sizeof(float), stream);

    // ---- branch 1: 3 IVoubottleneck blocks ----
    const float* cur = x;
    float* dst = bufA;
    for (int bi = 0; bi < 3; ++bi){
        float* st_t = stats + bi * 90;          // 3 x (15 sum + 15 sumsq)
        float* st_o = stats + 270 + bi * 180;   // 3 x (30 sum + 30 sumsq)
        conv1x1_k<<<dim3(844, 1, 3), 256, 0, stream>>>(
            cur, blk_w1 + bi * 1350, t_raw, st_t, 30, 15, 225, 64, 450, 216000, 30);
        invol_b1<5><<<113, 256, 0, stream>>>(cur, t_raw,          st_t,      blk_ig + (bi*3+0)*15, blk_ib + (bi*3+0)*15, blk_w2_5 + bi*750,  o_raw,          st_o);
        invol_b1<7><<<113, 256, 0, stream>>>(cur, t_raw + 216000, st_t + 30, blk_ig + (bi*3+1)*15, blk_ib + (bi*3+1)*15, blk_w2_7 + bi*1470, o_raw + 432000, st_o + 60);
        invol_b1<9><<<113, 256, 0, stream>>>(cur, t_raw + 432000, st_t + 60, blk_ig + (bi*3+2)*15, blk_ib + (bi*3+2)*15, blk_w2_9 + bi*2430, o_raw + 864000, st_o + 120);
        blockend<<<1688, 256, 0, stream>>>(o_raw, o_raw + 432000, o_raw + 864000,
                                           st_o, st_o + 60, st_o + 120,
                                           blk_g + bi * 90, blk_b + bi * 90, blk_conv + bi * 2700,
                                           cur, dst);
        cur = dst;
        dst = (bi == 0) ? bufB : bufA;
    }
    covpool<<<64, 256, 0, stream>>>(cur, feat1, 30, 225);

    // ---- branch 2: cross attention (aliases scratch; branch-1 uses are done) ----
    float* t_loc = scratch;
    float* t_glb = t_loc + 58752;
    float* locb  = t_glb + 58752;
    float* o_idn = locb + 117504;
    float* t3    = o_idn + 117504;
    float* o3    = t3 + 58752;
    float* o4b   = o3 + 117504;
    float* o5    = o4b + 117504;
    float* t4    = o5 + 58752;
    float* o6    = t4 + 29376;
    float* o7    = o6 + 58752;
    float* o8    = o7 + 58752;
    float* t5    = o8 + 29376;
    float* o9    = t5 + 14400;
    float* o10   = o9 + 29376;
    float* o11   = o10 + 29376;

    float* s_tloc = stats + 810;
    float* s_tglb = s_tloc + 204;
    float* s_t3   = s_tglb + 204;
    float* s_o3   = s_t3 + 204;
    float* s_t4   = s_o3 + 408;
    float* s_o6   = s_t4 + 102;
    float* s_t5   = s_o6 + 204;
    float* s_o9   = s_t5 + 50;

    conv1x1_k<<<230, 256, 0, stream>>>(y, loc_w1, t_loc, s_tloc, 204, 102, 9, 64, 0, 0, 0);
    conv1x1_k<<<230, 256, 0, stream>>>(y, glb_w1, t_glb, s_tglb, 204, 102, 9, 64, 0, 0, 0);
    invol_loc<<<459, 256, 0, stream>>>(y, t_loc, s_tloc, loc_g, loc_b, loc_w2, locb);
    invol_g1<<<59, 256, 0, stream>>>(y, t_glb, s_tglb, glb_g, glb_b, glb_w2, o_idn, nullptr, 204, 102, y, locb);
    conv1x1_k<<<230, 256, 0, stream>>>(o_idn, c3_w1, t3, s_t3, 204, 102, 9, 64, 0, 0, 0);
    invol_g1<<<59, 256, 0, stream>>>(o_idn, t3, s_t3, c3_g, c3_b, c3_w2, o3, s_o3, 204, 102, nullptr, nullptr);
    bn_relu_add<<<459, 256, 0, stream>>>(o3, s_o3, bn1g, bn1b, o_idn, o4b, 204, 9, 117504, 1.f / 576.f);
    conv1x1_k<<<230, 256, 0, stream>>>(o4b, p1, o5, nullptr, 204, 102, 9, 64, 0, 0, 0);
    conv1x1_k<<<115, 256, 0, stream>>>(o5, c4_w1, t4, s_t4, 102, 51, 9, 64, 0, 0, 0);
    invol_g1<<<30, 256, 0, stream>>>(o5, t4, s_t4, c4_g, c4_b, c4_w2, o6, s_o6, 102, 51, nullptr, nullptr);
    bn_relu_add<<<230, 256, 0, stream>>>(o6, s_o6, bn2g, bn2b, nullptr, o7, 102, 9, 58752, 1.f / 576.f);
    conv1x1_k<<<115, 256, 0, stream>>>(o7, p2, o8, nullptr, 102, 51, 9, 64, 0, 0, 0);
    conv1x1_k<<<57, 256, 0, stream>>>(o8, c5_w1, t5, s_t5, 51, 25, 9, 64, 0, 0, 0);
    invol_g1<<<16, 256, 0, stream>>>(o8, t5, s_t5, c5_g, c5_b, c5_w2, o9, s_o9, 51, 25, nullptr, nullptr);
    bn_relu_add<<<115, 256, 0, stream>>>(o9, s_o9, bn3g, bn3b, o8, o10, 51, 9, 29376, 1.f / 576.f);
    conv1x1_k<<<36, 256, 0, stream>>>(o10, p3, o11, nullptr, 51, 16, 9, 64, 0, 0, 0);
    covpool<<<64, 256, 0, stream>>>(o11, feat2, 16, 9);

    // ---- head ----
    head_k<<<1, 256, 0, stream>>>(feat1, feat2, hg, hb, lw, lb, (float*)d_out);
}

// Round 2
// 1743.473 us; speedup vs baseline: 1.2540x; 1.2540x over previous
//
#include <hip/hip_runtime.h>
#include <math.h>

#define EPS 1e-5f

__device__ inline void wave_red2(float& s1, float& s2){
    for (int off = 32; off; off >>= 1){
        s1 += __shfl_down(s1, off, 64);
        s2 += __shfl_down(s2, off, 64);
    }
}

// ---------------------------------------------------------------------------
// Generic conv1x1 (out[b,j,hw] = sum_c in[b,c,hw]*w[j,c]) with optional
// per-channel (sum, sumsq) stats accumulation. grid.z selects weight/out/stats
// slices. Requires (B*HW) % 64 == 0 so each wave has uniform j.
// ---------------------------------------------------------------------------
__global__ void conv1x1_k(const float* __restrict__ in, const float* __restrict__ w,
                          float* __restrict__ out, float* __restrict__ stats,
                          int Cin, int Cout, int HW, int B,
                          int wStrideZ, int outStrideZ, int statsStrideZ)
{
    const float* wz = w + (size_t)blockIdx.z * wStrideZ;
    float* oz = out + (size_t)blockIdx.z * outStrideZ;
    float* sz = stats ? stats + (size_t)blockIdx.z * statsStrideZ : nullptr;
    int npos = B * HW;
    int total = Cout * npos;
    int item = blockIdx.x * blockDim.x + threadIdx.x;
    if (item >= total) return;
    int j = item / npos;
    int pos = item - j * npos;
    int b = pos / HW, hw = pos - b * HW;
    const float* ip = in + (size_t)b * Cin * HW + hw;
    const float* wr = wz + (size_t)j * Cin;
    float acc = 0.f;
    #pragma unroll 4
    for (int c = 0; c < Cin; ++c) acc += ip[(size_t)c * HW] * wr[c];
    oz[(size_t)b * Cout * HW + (size_t)j * HW + hw] = acc;
    if (sz){
        float s1 = acc, s2 = acc * acc;
        wave_red2(s1, s2);
        if ((threadIdx.x & 63) == 0){
            atomicAdd(&sz[j], s1);
            atomicAdd(&sz[Cout + j], s2);
        }
    }
}

// ---------------------------------------------------------------------------
// Branch-1 wk generator: wk[r][pos] = sum_j relu(bn(t[j][pos])) * w2[r][j]
// r in [0, rows) where rows = 2*K*K; 5 rows per thread (t loaded once).
// w2 index is wave-uniform (chunk uniform since 14400 % 64 == 0) -> scalar.
// ---------------------------------------------------------------------------
__global__ void wkgen_b1(const float* __restrict__ t_raw, const float* __restrict__ tstats,
                         const float* __restrict__ tg, const float* __restrict__ tb,
                         const float* __restrict__ w2, float* __restrict__ wk, int rows)
{
    __shared__ float tsc[15], tsh[15];
    if (threadIdx.x < 15){
        int j = threadIdx.x;
        const float invN = 1.f / 14400.f;
        float mean = tstats[j] * invN;
        float var  = tstats[15 + j] * invN - mean * mean;
        float s = tg[j] * rsqrtf(var + EPS);
        tsc[j] = s; tsh[j] = tb[j] - mean * s;
    }
    __syncthreads();
    int nchunk = (rows + 4) / 5;
    int item = blockIdx.x * 256 + threadIdx.x;
    if (item >= nchunk * 14400) return;
    int chunk = item / 14400, pos = item - chunk * 14400;
    int b = pos / 225, hw = pos - b * 225;
    int r0 = chunk * 5;
    float acc[5] = {0.f, 0.f, 0.f, 0.f, 0.f};
    const float* tp = t_raw + (size_t)b * 3375 + hw;
    #pragma unroll
    for (int j = 0; j < 15; ++j){
        float t = tp[j * 225] * tsc[j] + tsh[j];
        t = t > 0.f ? t : 0.f;
        #pragma unroll
        for (int rr = 0; rr < 5; ++rr){
            int r = r0 + rr;
            acc[rr] += t * w2[(r < rows ? r : 0) * 15 + j];
        }
    }
    #pragma unroll
    for (int rr = 0; rr < 5; ++rr){
        int r = r0 + rr;
        if (r < rows) wk[(size_t)r * 14400 + pos] = acc[rr];
    }
}

// ---------------------------------------------------------------------------
// Branch-1 involution apply: one thread per (channel, position). 432000
// threads -> 1688 blocks. wk reads coalesced (stride 14400); window loads
// predicated. Accumulates per-channel stats (c wave-uniform: 14400%64==0).
// ---------------------------------------------------------------------------
template<int K>
__global__ void apply_b1(const float* __restrict__ in, const float* __restrict__ wk,
                         float* __restrict__ o_raw, float* __restrict__ ostats)
{
    constexpr int KK = K * K, P = (K - 1) / 2;
    int item = blockIdx.x * 256 + threadIdx.x;
    if (item >= 30 * 14400) return;
    int c = item / 14400, pos = item - c * 14400;
    int b = pos / 225, hw = pos - b * 225;
    int h = hw / 15, w = hw - h * 15;
    int g = c / 15;
    const float* inc = in + (size_t)b * 6750 + c * 225;
    const float* wkb = wk + (size_t)g * KK * 14400 + pos;
    float acc = 0.f;
    #pragma unroll
    for (int ki = 0; ki < K; ++ki){
        int hh = h + ki - P;
        bool hok = (hh >= 0) && (hh < 15);
        #pragma unroll
        for (int kj = 0; kj < K; ++kj){
            int ww = w + kj - P;
            bool ok = hok && (ww >= 0) && (ww < 15);
            float v = ok ? inc[hh * 15 + ww] : 0.f;
            acc += wkb[(size_t)(ki * K + kj) * 14400] * v;
        }
    }
    o_raw[(size_t)b * 6750 + c * 225 + hw] = acc;
    float s1 = acc, s2 = acc * acc;
    wave_red2(s1, s2);
    if ((threadIdx.x & 63) == 0){
        atomicAdd(&ostats[c], s1);
        atomicAdd(&ostats[30 + c], s2);
    }
}

// ---------------------------------------------------------------------------
// Branch-1 block end: out_new = conv1x1(concat(relu(bn(o_ii))), conv) + out_old
// ---------------------------------------------------------------------------
__global__ void blockend(const float* __restrict__ o0, const float* __restrict__ o1,
                         const float* __restrict__ o2,
                         const float* __restrict__ s0, const float* __restrict__ s1,
                         const float* __restrict__ s2,
                         const float* __restrict__ g, const float* __restrict__ bb,
                         const float* __restrict__ conv,
                         const float* __restrict__ oldout, float* __restrict__ newout)
{
    __shared__ float sc[90], sh[90];
    int tid = threadIdx.x;
    if (tid < 90){
        int ii = tid / 30, cc = tid - ii * 30;
        const float* st = ii == 0 ? s0 : (ii == 1 ? s1 : s2);
        const float invN = 1.f / 14400.f;
        float mean = st[cc] * invN;
        float var = st[30 + cc] * invN - mean * mean;
        float s = g[tid] * rsqrtf(var + EPS);
        sc[tid] = s; sh[tid] = bb[tid] - mean * s;
    }
    __syncthreads();
    int item = blockIdx.x * 256 + tid;
    if (item >= 432000) return;
    int c = item / 14400, pos = item - c * 14400;
    int b = pos / 225, hw = pos - b * 225;
    float acc = oldout[(size_t)b * 30 * 225 + c * 225 + hw];
    const float* cr = conv + c * 90;
    const float* bases[3] = {o0, o1, o2};
    #pragma unroll
    for (int ii = 0; ii < 3; ++ii){
        const float* op = bases[ii] + (size_t)b * 30 * 225 + hw;
        #pragma unroll 6
        for (int cc = 0; cc < 30; ++cc){
            float v = op[cc * 225] * sc[ii * 30 + cc] + sh[ii * 30 + cc];
            v = v > 0.f ? v : 0.f;
            acc += v * cr[ii * 30 + cc];
        }
    }
    newout[(size_t)b * 30 * 225 + c * 225 + hw] = acc;
}

// ---------------------------------------------------------------------------
// Branch-2 wk generator (k=3, H=W=3, npos=576):
// wk[r][pos] = sum_j relu(bn(t[j][pos])) * w2[r][j], 6 rows/thread.
// Handles both groups==C (rows = C*9, e.g. 1836) and groups==1 (rows = 9).
// ---------------------------------------------------------------------------
__global__ void invol3_wkgen(const float* __restrict__ t_raw, const float* __restrict__ tstats,
                             const float* __restrict__ tg, const float* __restrict__ tb,
                             const float* __restrict__ w2, float* __restrict__ wk,
                             int rows, int Ct)
{
    __shared__ float tsc[102], tsh[102];
    const float invN = 1.f / 576.f;
    for (int j = threadIdx.x; j < Ct; j += 256){
        float mean = tstats[j] * invN;
        float var  = tstats[Ct + j] * invN - mean * mean;
        float s = tg[j] * rsqrtf(var + EPS);
        tsc[j] = s; tsh[j] = tb[j] - mean * s;
    }
    __syncthreads();
    int nchunk = (rows + 5) / 6;
    int item = blockIdx.x * 256 + threadIdx.x;
    if (item >= nchunk * 576) return;
    int chunk = item / 576, pos = item - chunk * 576;
    int b = pos / 9, hw = pos - b * 9;
    int r0 = chunk * 6;
    float acc[6] = {0.f, 0.f, 0.f, 0.f, 0.f, 0.f};
    const float* tp = t_raw + (size_t)b * Ct * 9 + hw;
    #pragma unroll 2
    for (int j = 0; j < Ct; ++j){
        float t = tp[j * 9] * tsc[j] + tsh[j];
        t = t > 0.f ? t : 0.f;
        #pragma unroll
        for (int rr = 0; rr < 6; ++rr){
            int r = r0 + rr;
            acc[rr] += t * w2[(size_t)(r < rows ? r : 0) * Ct + j];
        }
    }
    #pragma unroll
    for (int rr = 0; rr < 6; ++rr){
        int r = r0 + rr;
        if (r < rows) wk[(size_t)r * 576 + pos] = acc[rr];
    }
}

// ---------------------------------------------------------------------------
// Branch-2 involution apply (k=3): one thread per (channel, position).
// rowStrideC = 9 for groups==C (per-channel wk rows), 0 for groups==1.
// Epilogues: crossmul (ymul*(locadd+val)), stats, or plain write.
// c is wave-uniform (576 % 64 == 0).
// ---------------------------------------------------------------------------
__global__ void invol3_apply(const float* __restrict__ pin, const float* __restrict__ wk,
                             float* __restrict__ out, float* __restrict__ ostats,
                             int C, int rowStrideC,
                             const float* __restrict__ ymul, const float* __restrict__ locadd)
{
    int item = blockIdx.x * 256 + threadIdx.x;
    if (item >= C * 576) return;
    int c = item / 576, pos = item - c * 576;
    int b = pos / 9, hw = pos - b * 9;
    int h = hw / 3, w = hw - h * 3;
    const float* pb = pin + (size_t)b * C * 9 + c * 9;
    const float* wkb = wk + (size_t)c * rowStrideC * 576 + pos;
    float acc = 0.f;
    #pragma unroll
    for (int ki = 0; ki < 3; ++ki){
        int hh = h + ki - 1;
        bool hok = (hh >= 0) && (hh < 3);
        #pragma unroll
        for (int kj = 0; kj < 3; ++kj){
            int ww = w + kj - 1;
            bool ok = hok && (ww >= 0) && (ww < 3);
            float v = ok ? pb[hh * 3 + ww] : 0.f;
            acc += wkb[(size_t)(ki * 3 + kj) * 576] * v;
        }
    }
    size_t oi = (size_t)b * C * 9 + c * 9 + hw;
    if (ymul){
        out[oi] = ymul[oi] * (locadd[oi] + acc);
    } else if (ostats){
        out[oi] = acc;
        float s1 = acc, s2 = acc * acc;
        wave_red2(s1, s2);
        if ((threadIdx.x & 63) == 0){
            atomicAdd(&ostats[c], s1);
            atomicAdd(&ostats[C + c], s2);
        }
    } else {
        out[oi] = acc;
    }
}

// ---------------------------------------------------------------------------
// Elementwise: out = relu(bn(in)) [+ res]
// ---------------------------------------------------------------------------
__global__ void bn_relu_add(const float* __restrict__ in, const float* __restrict__ stats,
                            const float* __restrict__ g, const float* __restrict__ bta,
                            const float* __restrict__ res, float* __restrict__ out,
                            int C, int HW, int total, float invN)
{
    int i = blockIdx.x * 256 + threadIdx.x;
    if (i >= total) return;
    int c = (i / HW) % C;
    float mean = stats[c] * invN;
    float var = stats[C + c] * invN - mean * mean;
    float sc = g[c] * rsqrtf(var + EPS);
    float v = (in[i] - mean) * sc + bta[c];
    v = v > 0.f ? v : 0.f;
    if (res) v += res[i];
    out[i] = v;
}

// ---------------------------------------------------------------------------
// GlobalCovPooling: one workgroup per batch element, everything in LDS.
// Faithful to the reference incl. ELEMENTWISE Y-update in Newton-Schulz.
// Templated on (C,N) so inner loops unroll.
// ---------------------------------------------------------------------------
template<int C, int N>
__global__ void covpool(const float* __restrict__ in, float* __restrict__ feat)
{
    __shared__ float X[N * C];
    __shared__ float Ybuf[C * C], Mbuf[C * C], Zbuf[C * C], Z2buf[C * C];
    __shared__ float mu[C];
    __shared__ float scal[2];
    int b = blockIdx.x, tid = threadIdx.x;
    const float* ib = in + (size_t)b * C * N;
    for (int i = tid; i < N * C; i += 256){
        int n = i / C, c = i - n * C;
        X[i] = ib[(size_t)c * N + n];
    }
    __syncthreads();
    if (tid < C){
        float s = 0.f;
        #pragma unroll 5
        for (int n = 0; n < N; ++n) s += X[n * C + tid];
        mu[tid] = s / (float)N;
    }
    __syncthreads();
    constexpr int CC = C * C;
    for (int i = tid; i < CC; i += 256){
        int c = i / C, d = i - c * C;
        float s = 0.f;
        #pragma unroll 5
        for (int n = 0; n < N; ++n) s += X[n * C + c] * X[n * C + d];
        Ybuf[i] = s / (float)N - mu[c] * mu[d];
    }
    __syncthreads();
    if (tid == 0){
        float tr = 0.f;
        for (int c = 0; c < C; ++c) tr += Ybuf[c * C + c];
        scal[0] = 1.f / tr;
    }
    __syncthreads();
    for (int i = tid; i < CC; i += 256){
        int c = i / C, d = i - c * C;
        Ybuf[i] *= scal[0];
        Zbuf[i] = (c == d) ? 1.f : 0.f;
    }
    __syncthreads();
    float* zs = Zbuf; float* zd = Z2buf;
    for (int it = 0; it < 6; ++it){
        for (int i = tid; i < CC; i += 256){
            int c = i / C, d = i - c * C;
            float s = 0.f;
            #pragma unroll 6
            for (int e = 0; e < C; ++e) s += zs[c * C + e] * Ybuf[e * C + d];
            Mbuf[i] = ((c == d) ? 3.f : 0.f) - s;
        }
        __syncthreads();
        for (int i = tid; i < CC; i += 256){
            int c = i / C, d = i - c * C;
            float s = 0.f;
            #pragma unroll 6
            for (int e = 0; e < C; ++e) s += Mbuf[c * C + e] * zs[e * C + d];
            zd[i] = 0.5f * s;
        }
        for (int i = tid; i < CC; i += 256) Ybuf[i] *= 0.5f * Mbuf[i];   // elementwise, as in source
        __syncthreads();
        float* t = zs; zs = zd; zd = t;
    }
    if (tid == 0){
        float tr = 0.f;
        for (int c = 0; c < C; ++c) tr += Ybuf[c * C + c];
        scal[1] = sqrtf(tr);
    }
    __syncthreads();
    if (tid < C){
        float s = 0.f;
        #pragma unroll 6
        for (int c = 0; c < C; ++c) s += Ybuf[c * C + tid];
        feat[(size_t)b * C + tid] = scal[1] * s / (float)C;
    }
}

// ---------------------------------------------------------------------------
// Head: concat feats, BN over batch, ReLU, linear, softmax. Single workgroup.
// ---------------------------------------------------------------------------
__global__ void head_k(const float* __restrict__ feat1, const float* __restrict__ feat2,
                       const float* __restrict__ hg, const float* __restrict__ hb,
                       const float* __restrict__ lw, const float* __restrict__ lb,
                       float* __restrict__ out)
{
    __shared__ float f[46 * 64];
    int tid = threadIdx.x;
    for (int i = tid; i < 46 * 64; i += 256){
        int ch = i / 64, b = i - ch * 64;
        f[i] = ch < 30 ? feat1[b * 30 + ch] : feat2[b * 16 + (ch - 30)];
    }
    __syncthreads();
    if (tid < 46){
        float s = 0.f, s2 = 0.f;
        for (int b = 0; b < 64; ++b){ float v = f[tid * 64 + b]; s += v; s2 += v * v; }
        float mean = s / 64.f, var = s2 / 64.f - mean * mean;
        float sc = hg[tid] * rsqrtf(var + EPS), sh = hb[tid] - mean * sc;
        for (int b = 0; b < 64; ++b){
            float v = f[tid * 64 + b] * sc + sh;
            f[tid * 64 + b] = v > 0.f ? v : 0.f;
        }
    }
    __syncthreads();
    if (tid < 64){
        int b = tid;
        float l[16];
        float m = -1e30f;
        for (int o = 0; o < 16; ++o){
            float a = lb[o];
            for (int ch = 0; ch < 46; ++ch) a += f[ch * 64 + b] * lw[o * 46 + ch];
            l[o] = a; m = fmaxf(m, a);
        }
        float se = 0.f;
        for (int o = 0; o < 16; ++o){ l[o] = expf(l[o] - m); se += l[o]; }
        float inv = 1.f / se;
        for (int o = 0; o < 16; ++o) out[b * 16 + o] = l[o] * inv;
    }
}

extern "C" void kernel_launch(void* const* d_in, const int* in_sizes, int n_in,
                              void* d_out, int out_size, void* d_ws, size_t ws_size,
                              hipStream_t stream)
{
    (void)in_sizes; (void)n_in; (void)out_size; (void)ws_size;
    const float* x        = (const float*)d_in[0];
    const float* y        = (const float*)d_in[1];
    const float* blk_w1   = (const float*)d_in[2];
    const float* blk_ig   = (const float*)d_in[3];
    const float* blk_ib   = (const float*)d_in[4];
    const float* blk_w2_5 = (const float*)d_in[5];
    const float* blk_w2_7 = (const float*)d_in[6];
    const float* blk_w2_9 = (const float*)d_in[7];
    const float* blk_g    = (const float*)d_in[8];
    const float* blk_b    = (const float*)d_in[9];
    const float* blk_conv = (const float*)d_in[10];
    const float* loc_w1 = (const float*)d_in[11];
    const float* loc_g  = (const float*)d_in[12];
    const float* loc_b  = (const float*)d_in[13];
    const float* loc_w2 = (const float*)d_in[14];
    const float* glb_w1 = (const float*)d_in[15];
    const float* glb_g  = (const float*)d_in[16];
    const float* glb_b  = (const float*)d_in[17];
    const float* glb_w2 = (const float*)d_in[18];
    const float* c3_w1 = (const float*)d_in[19];
    const float* c3_g  = (const float*)d_in[20];
    const float* c3_b  = (const float*)d_in[21];
    const float* c3_w2 = (const float*)d_in[22];
    const float* c4_w1 = (const float*)d_in[23];
    const float* c4_g  = (const float*)d_in[24];
    const float* c4_b  = (const float*)d_in[25];
    const float* c4_w2 = (const float*)d_in[26];
    const float* c5_w1 = (const float*)d_in[27];
    const float* c5_g  = (const float*)d_in[28];
    const float* c5_b  = (const float*)d_in[29];
    const float* c5_w2 = (const float*)d_in[30];
    const float* p1 = (const float*)d_in[31];
    const float* p2 = (const float*)d_in[32];
    const float* p3 = (const float*)d_in[33];
    const float* bn1g = (const float*)d_in[34];
    const float* bn1b = (const float*)d_in[35];
    const float* bn2g = (const float*)d_in[36];
    const float* bn2b = (const float*)d_in[37];
    const float* bn3g = (const float*)d_in[38];
    const float* bn3b = (const float*)d_in[39];
    const float* hg = (const float*)d_in[40];
    const float* hb = (const float*)d_in[41];
    const float* lw = (const float*)d_in[42];
    const float* lb = (const float*)d_in[43];

    float* ws = (float*)d_ws;
    size_t off = 0;
    auto alloc = [&](size_t n){ float* p = ws + off; off += n; return p; };
    float* bufA    = alloc(432000);
    float* bufB    = alloc(432000);
    float* scratch = alloc(1944000);   // branch1 t_raw(3)+o_raw(3); branch2 aliases this
    float* wkbuf   = alloc(2332800);   // dynamic-kernel scratch (max 162 x 14400), reused
    float* feat1   = alloc(64 * 30);
    float* feat2   = alloc(64 * 16);
    float* stats   = alloc(2288);

    float* t_raw = scratch;            // 3 x 216000
    float* o_raw = scratch + 648000;   // 3 x 432000

    hipMemsetAsync(stats, 0, 2288 * sizeof(float), stream);

    // ---- branch 1: 3 IVoubottleneck blocks ----
    const float* cur = x;
    float* dst = bufA;
    for (int bi = 0; bi < 3; ++bi){
        float* st_t = stats + bi * 90;          // 3 x (15 sum + 15 sumsq)
        float* st_o = stats + 270 + bi * 180;   // 3 x (30 sum + 30 sumsq)
        conv1x1_k<<<dim3(844, 1, 3), 256, 0, stream>>>(
            cur, blk_w1 + bi * 1350, t_raw, st_t, 30, 15, 225, 64, 450, 216000, 30);
        // K=5 (rows=50, nchunk=10)
        wkgen_b1<<<563, 256, 0, stream>>>(t_raw, st_t,
            blk_ig + (bi*3+0)*15, blk_ib + (bi*3+0)*15, blk_w2_5 + bi*750, wkbuf, 50);
        apply_b1<5><<<1688, 256, 0, stream>>>(cur, wkbuf, o_raw, st_o);
        // K=7 (rows=98, nchunk=20)
        wkgen_b1<<<1125, 256, 0, stream>>>(t_raw + 216000, st_t + 30,
            blk_ig + (bi*3+1)*15, blk_ib + (bi*3+1)*15, blk_w2_7 + bi*1470, wkbuf, 98);
        apply_b1<7><<<1688, 256, 0, stream>>>(cur, wkbuf, o_raw + 432000, st_o + 60);
        // K=9 (rows=162, nchunk=33)
        wkgen_b1<<<1857, 256, 0, stream>>>(t_raw + 432000, st_t + 60,
            blk_ig + (bi*3+2)*15, blk_ib + (bi*3+2)*15, blk_w2_9 + bi*2430, wkbuf, 162);
        apply_b1<9><<<1688, 256, 0, stream>>>(cur, wkbuf, o_raw + 864000, st_o + 120);

        blockend<<<1688, 256, 0, stream>>>(o_raw, o_raw + 432000, o_raw + 864000,
                                           st_o, st_o + 60, st_o + 120,
                                           blk_g + bi * 90, blk_b + bi * 90, blk_conv + bi * 2700,
                                           cur, dst);
        cur = dst;
        dst = (bi == 0) ? bufB : bufA;
    }
    covpool<30, 225><<<64, 256, 0, stream>>>(cur, feat1);

    // ---- branch 2: cross attention (aliases scratch; branch-1 uses are done) ----
    float* t_loc = scratch;
    float* t_glb = t_loc + 58752;
    float* locb  = t_glb + 58752;
    float* o_idn = locb + 117504;
    float* t3    = o_idn + 117504;
    float* o3    = t3 + 58752;
    float* o4b   = o3 + 117504;
    float* o5    = o4b + 117504;
    float* t4    = o5 + 58752;
    float* o6    = t4 + 29376;
    float* o7    = o6 + 58752;
    float* o8    = o7 + 58752;
    float* t5    = o8 + 29376;
    float* o9    = t5 + 14400;
    float* o10   = o9 + 29376;
    float* o11   = o10 + 29376;

    float* s_tloc = stats + 810;
    float* s_tglb = s_tloc + 204;
    float* s_t3   = s_tglb + 204;
    float* s_o3   = s_t3 + 204;
    float* s_t4   = s_o3 + 408;
    float* s_o6   = s_t4 + 102;
    float* s_t5   = s_o6 + 204;
    float* s_o9   = s_t5 + 50;

    conv1x1_k<<<230, 256, 0, stream>>>(y, loc_w1, t_loc, s_tloc, 204, 102, 9, 64, 0, 0, 0);
    conv1x1_k<<<230, 256, 0, stream>>>(y, glb_w1, t_glb, s_tglb, 204, 102, 9, 64, 0, 0, 0);
    // loc: groups == C == 204 -> rows = 1836, nchunk = 306
    invol3_wkgen<<<689, 256, 0, stream>>>(t_loc, s_tloc, loc_g, loc_b, loc_w2, wkbuf, 1836, 102);
    invol3_apply<<<459, 256, 0, stream>>>(y, wkbuf, locb, nullptr, 204, 9, nullptr, nullptr);
    // glb: groups == 1 -> rows = 9
    invol3_wkgen<<<5, 256, 0, stream>>>(t_glb, s_tglb, glb_g, glb_b, glb_w2, wkbuf, 9, 102);
    invol3_apply<<<459, 256, 0, stream>>>(y, wkbuf, o_idn, nullptr, 204, 0, y, locb);
    // c3
    conv1x1_k<<<230, 256, 0, stream>>>(o_idn, c3_w1, t3, s_t3, 204, 102, 9, 64, 0, 0, 0);
    invol3_wkgen<<<5, 256, 0, stream>>>(t3, s_t3, c3_g, c3_b, c3_w2, wkbuf, 9, 102);
    invol3_apply<<<459, 256, 0, stream>>>(o_idn, wkbuf, o3, s_o3, 204, 0, nullptr, nullptr);
    bn_relu_add<<<459, 256, 0, stream>>>(o3, s_o3, bn1g, bn1b, o_idn, o4b, 204, 9, 117504, 1.f / 576.f);
    conv1x1_k<<<230, 256, 0, stream>>>(o4b, p1, o5, nullptr, 204, 102, 9, 64, 0, 0, 0);
    // c4
    conv1x1_k<<<115, 256, 0, stream>>>(o5, c4_w1, t4, s_t4, 102, 51, 9, 64, 0, 0, 0);
    invol3_wkgen<<<5, 256, 0, stream>>>(t4, s_t4, c4_g, c4_b, c4_w2, wkbuf, 9, 51);
    invol3_apply<<<230, 256, 0, stream>>>(o5, wkbuf, o6, s_o6, 102, 0, nullptr, nullptr);
    bn_relu_add<<<230, 256, 0, stream>>>(o6, s_o6, bn2g, bn2b, nullptr, o7, 102, 9, 58752, 1.f / 576.f);
    conv1x1_k<<<115, 256, 0, stream>>>(o7, p2, o8, nullptr, 102, 51, 9, 64, 0, 0, 0);
    // c5
    conv1x1_k<<<57, 256, 0, stream>>>(o8, c5_w1, t5, s_t5, 51, 25, 9, 64, 0, 0, 0);
    invol3_wkgen<<<5, 256, 0, stream>>>(t5, s_t5, c5_g, c5_b, c5_w2, wkbuf, 9, 25);
    invol3_apply<<<115, 256, 0, stream>>>(o8, wkbuf, o9, s_o9, 51, 0, nullptr, nullptr);
    bn_relu_add<<<115, 256, 0, stream>>>(o9, s_o9, bn3g, bn3b, o8, o10, 51, 9, 29376, 1.f / 576.f);
    conv1x1_k<<<36, 256, 0, stream>>>(o10, p3, o11, nullptr, 51, 16, 9, 64, 0, 0, 0);
    covpool<16, 9><<<64, 256, 0, stream>>>(o11, feat2);

    // ---- head ----
    head_k<<<1, 256, 0, stream>>>(feat1, feat2, hg, hb, lw, lb, (float*)d_out);
}

// Round 3
// 1537.480 us; speedup vs baseline: 1.4220x; 1.1340x over previous
//
#include <hip/hip_runtime.h>
#include <math.h>

#define EPS 1e-5f

__device__ inline void wave_red2(float& s1, float& s2){
    for (int off = 32; off; off >>= 1){
        s1 += __shfl_down(s1, off, 64);
        s2 += __shfl_down(s2, off, 64);
    }
}

// ---------------------------------------------------------------------------
// Generic conv1x1 (out[b,j,hw] = sum_c in[b,c,hw]*w[j,c]) with optional
// per-channel (sum, sumsq) stats accumulation. grid.z selects weight/out/stats
// slices. Requires (B*HW) % 64 == 0 so each wave has uniform j.
// ---------------------------------------------------------------------------
__global__ void conv1x1_k(const float* __restrict__ in, const float* __restrict__ w,
                          float* __restrict__ out, float* __restrict__ stats,
                          int Cin, int Cout, int HW, int B,
                          int wStrideZ, int outStrideZ, int statsStrideZ)
{
    const float* wz = w + (size_t)blockIdx.z * wStrideZ;
    float* oz = out + (size_t)blockIdx.z * outStrideZ;
    float* sz = stats ? stats + (size_t)blockIdx.z * statsStrideZ : nullptr;
    int npos = B * HW;
    int total = Cout * npos;
    int item = blockIdx.x * blockDim.x + threadIdx.x;
    if (item >= total) return;
    int j = item / npos;
    int pos = item - j * npos;
    int b = pos / HW, hw = pos - b * HW;
    const float* ip = in + (size_t)b * Cin * HW + hw;
    const float* wr = wz + (size_t)j * Cin;
    float acc = 0.f;
    #pragma unroll 4
    for (int c = 0; c < Cin; ++c) acc += ip[(size_t)c * HW] * wr[c];
    oz[(size_t)b * Cout * HW + (size_t)j * HW + hw] = acc;
    if (sz){
        float s1 = acc, s2 = acc * acc;
        wave_red2(s1, s2);
        if ((threadIdx.x & 63) == 0){
            atomicAdd(&sz[j], s1);
            atomicAdd(&sz[Cout + j], s2);
        }
    }
}

// ---------------------------------------------------------------------------
// FUSED branch-1 involution: one block per (b, group, ksize). Per-position
// dynamic kernel wk[K*K] lives in REGISTERS; t (BN+ReLU'd) and the group's
// input plane live in LDS. No wk global round-trip at all.
// Thread = one position p (225 of 256 active); all 256 stay for shuffles.
// ---------------------------------------------------------------------------
template<int K>
__device__ void invol_b1_dev(const float* __restrict__ in, const float* __restrict__ t_raw,
                             const float* __restrict__ tstats,
                             const float* __restrict__ tg, const float* __restrict__ tb,
                             const float* __restrict__ w2,
                             float* __restrict__ o_raw, float* __restrict__ ostats,
                             float* lds)
{
    constexpr int KK = K * K, P = (K - 1) / 2;
    float* t_s  = lds;               // 3375: relu(bn(t)) [15][225]
    float* in_s = lds + 3375;        // 3375: group input [15][225]
    float* w2_s = lds + 6750;        // KK*15 (<= 1215)
    float* scb  = lds + 6750 + 1215; // 15
    float* shb  = scb + 15;          // 15
    int tid = threadIdx.x;
    int b = blockIdx.x, g = blockIdx.y;

    if (tid < 15){
        const float invN = 1.f / 14400.f;
        float mean = tstats[tid] * invN;
        float var  = tstats[15 + tid] * invN - mean * mean;
        float s = tg[tid] * rsqrtf(var + EPS);
        scb[tid] = s; shb[tid] = tb[tid] - mean * s;
    }
    const float* w2g = w2 + (size_t)g * KK * 15;
    for (int i = tid; i < KK * 15; i += 256) w2_s[i] = w2g[i];
    const float* inb = in + (size_t)b * 6750 + (size_t)g * 3375;
    for (int i = tid; i < 3375; i += 256) in_s[i] = inb[i];
    const float* trb = t_raw + (size_t)b * 3375;
    for (int i = tid; i < 3375; i += 256) t_s[i] = trb[i];
    __syncthreads();
    // BN+ReLU t in place
    for (int i = tid; i < 3375; i += 256){
        int j = i / 225;
        float v = t_s[i] * scb[j] + shb[j];
        t_s[i] = v > 0.f ? v : 0.f;
    }
    __syncthreads();

    bool act = tid < 225;
    int p = act ? tid : 224;
    int h = p / 15, w = p - h * 15;

    float treg[15];
    #pragma unroll
    for (int j = 0; j < 15; ++j) treg[j] = t_s[j * 225 + p];

    float wk[KK];
    #pragma unroll
    for (int kk = 0; kk < KK; ++kk){
        float a = 0.f;
        #pragma unroll
        for (int j = 0; j < 15; ++j) a += treg[j] * w2_s[kk * 15 + j];
        wk[kk] = a;
    }

    float* ob = o_raw + (size_t)b * 6750 + (size_t)g * 3375;
    for (int cc = 0; cc < 15; ++cc){
        float acc = 0.f;
        const float* ic = in_s + cc * 225;
        #pragma unroll
        for (int ki = 0; ki < K; ++ki){
            int hh = h + ki - P;
            bool hok = (unsigned)hh < 15u;
            #pragma unroll
            for (int kj = 0; kj < K; ++kj){
                int ww = w + kj - P;
                bool ok = hok && ((unsigned)ww < 15u);
                float v = ic[ok ? hh * 15 + ww : 0];
                acc += wk[ki * K + kj] * (ok ? v : 0.f);
            }
        }
        float val = act ? acc : 0.f;
        if (act) ob[cc * 225 + p] = val;
        float s1 = val, s2 = val * val;
        wave_red2(s1, s2);
        if ((tid & 63) == 0){
            atomicAdd(&ostats[g * 15 + cc], s1);
            atomicAdd(&ostats[30 + g * 15 + cc], s2);
        }
    }
}

__global__ void invol_b1_all(const float* __restrict__ in, const float* __restrict__ t_raw3,
                             const float* __restrict__ tstats3,
                             const float* __restrict__ tg3, const float* __restrict__ tb3,
                             const float* __restrict__ w2_5, const float* __restrict__ w2_7,
                             const float* __restrict__ w2_9,
                             float* __restrict__ o_raw3, float* __restrict__ ostats3)
{
    extern __shared__ float lds[];
    int ii = blockIdx.z;
    if (ii == 0)
        invol_b1_dev<5>(in, t_raw3,          tstats3,      tg3,      tb3,      w2_5, o_raw3,          ostats3,       lds);
    else if (ii == 1)
        invol_b1_dev<7>(in, t_raw3 + 216000, tstats3 + 30, tg3 + 15, tb3 + 15, w2_7, o_raw3 + 432000, ostats3 + 60,  lds);
    else
        invol_b1_dev<9>(in, t_raw3 + 432000, tstats3 + 60, tg3 + 30, tb3 + 30, w2_9, o_raw3 + 864000, ostats3 + 120, lds);
}

// ---------------------------------------------------------------------------
// Branch-1 block end: out_new = conv1x1(concat(relu(bn(o_ii))), conv) + out_old
// ---------------------------------------------------------------------------
__global__ void blockend(const float* __restrict__ o0, const float* __restrict__ o1,
                         const float* __restrict__ o2,
                         const float* __restrict__ s0, const float* __restrict__ s1,
                         const float* __restrict__ s2,
                         const float* __restrict__ g, const float* __restrict__ bb,
                         const float* __restrict__ conv,
                         const float* __restrict__ oldout, float* __restrict__ newout)
{
    __shared__ float sc[90], sh[90];
    int tid = threadIdx.x;
    if (tid < 90){
        int ii = tid / 30, cc = tid - ii * 30;
        const float* st = ii == 0 ? s0 : (ii == 1 ? s1 : s2);
        const float invN = 1.f / 14400.f;
        float mean = st[cc] * invN;
        float var = st[30 + cc] * invN - mean * mean;
        float s = g[tid] * rsqrtf(var + EPS);
        sc[tid] = s; sh[tid] = bb[tid] - mean * s;
    }
    __syncthreads();
    int item = blockIdx.x * 256 + tid;
    if (item >= 432000) return;
    int c = item / 14400, pos = item - c * 14400;
    int b = pos / 225, hw = pos - b * 225;
    float acc = oldout[(size_t)b * 6750 + c * 225 + hw];
    const float* cr = conv + c * 90;
    const float* bases[3] = {o0, o1, o2};
    #pragma unroll
    for (int ii = 0; ii < 3; ++ii){
        const float* op = bases[ii] + (size_t)b * 6750 + hw;
        #pragma unroll 6
        for (int cc = 0; cc < 30; ++cc){
            float v = op[cc * 225] * sc[ii * 30 + cc] + sh[ii * 30 + cc];
            v = v > 0.f ? v : 0.f;
            acc += v * cr[ii * 30 + cc];
        }
    }
    newout[(size_t)b * 6750 + c * 225 + hw] = acc;
}

// ---------------------------------------------------------------------------
// Branch-2 wk generator (k=3, npos=576): wk[r][pos] = sum_j relu(bn(t)) * w2.
// Handles rows = C*9 (groups==C) and rows = 9 (groups==1).
// ---------------------------------------------------------------------------
__global__ void invol3_wkgen(const float* __restrict__ t_raw, const float* __restrict__ tstats,
                             const float* __restrict__ tg, const float* __restrict__ tb,
                             const float* __restrict__ w2, float* __restrict__ wk,
                             int rows, int Ct)
{
    __shared__ float tsc[102], tsh[102];
    const float invN = 1.f / 576.f;
    for (int j = threadIdx.x; j < Ct; j += 256){
        float mean = tstats[j] * invN;
        float var  = tstats[Ct + j] * invN - mean * mean;
        float s = tg[j] * rsqrtf(var + EPS);
        tsc[j] = s; tsh[j] = tb[j] - mean * s;
    }
    __syncthreads();
    int nchunk = (rows + 5) / 6;
    int item = blockIdx.x * 256 + threadIdx.x;
    if (item >= nchunk * 576) return;
    int chunk = item / 576, pos = item - chunk * 576;
    int b = pos / 9, hw = pos - b * 9;
    int r0 = chunk * 6;
    float acc[6] = {0.f, 0.f, 0.f, 0.f, 0.f, 0.f};
    const float* tp = t_raw + (size_t)b * Ct * 9 + hw;
    #pragma unroll 2
    for (int j = 0; j < Ct; ++j){
        float t = tp[j * 9] * tsc[j] + tsh[j];
        t = t > 0.f ? t : 0.f;
        #pragma unroll
        for (int rr = 0; rr < 6; ++rr){
            int r = r0 + rr;
            acc[rr] += t * w2[(size_t)(r < rows ? r : 0) * Ct + j];
        }
    }
    #pragma unroll
    for (int rr = 0; rr < 6; ++rr){
        int r = r0 + rr;
        if (r < rows) wk[(size_t)r * 576 + pos] = acc[rr];
    }
}

// ---------------------------------------------------------------------------
// Fused loc+glb involutions + cross multiply: o = y * (loc(y) + glb(y)).
// Shares the 3x3 window loads between both involutions.
// ---------------------------------------------------------------------------
__global__ void crossatt_apply(const float* __restrict__ y, const float* __restrict__ wkloc,
                               const float* __restrict__ wkglb, float* __restrict__ out)
{
    int item = blockIdx.x * 256 + threadIdx.x;
    if (item >= 204 * 576) return;
    int c = item / 576, pos = item - c * 576;
    int b = pos / 9, hw = pos - b * 9;
    int h = hw / 3, w = hw - h * 3;
    const float* pb = y + (size_t)b * 1836 + c * 9;
    const float* wl = wkloc + (size_t)c * 9 * 576 + pos;
    const float* wg = wkglb + pos;
    float la = 0.f, ga = 0.f;
    float center = pb[hw];
    #pragma unroll
    for (int ki = 0; ki < 3; ++ki){
        int hh = h + ki - 1;
        bool hok = (unsigned)hh < 3u;
        #pragma unroll
        for (int kj = 0; kj < 3; ++kj){
            int ww = w + kj - 1;
            bool ok = hok && ((unsigned)ww < 3u);
            float v = ok ? pb[hh * 3 + ww] : 0.f;
            int kk = ki * 3 + kj;
            la += wl[(size_t)kk * 576] * v;
            ga += wg[(size_t)kk * 576] * v;
        }
    }
    out[(size_t)b * 1836 + c * 9 + hw] = center * (la + ga);
}

// ---------------------------------------------------------------------------
// Branch-2 groups==1 involution apply (wk shared by all channels).
// Epilogue: write + per-channel stats.
// ---------------------------------------------------------------------------
__global__ void invol3_apply(const float* __restrict__ pin, const float* __restrict__ wk,
                             float* __restrict__ out, float* __restrict__ ostats, int C)
{
    int item = blockIdx.x * 256 + threadIdx.x;
    if (item >= C * 576) return;
    int c = item / 576, pos = item - c * 576;
    int b = pos / 9, hw = pos - b * 9;
    int h = hw / 3, w = hw - h * 3;
    const float* pb = pin + (size_t)b * C * 9 + c * 9;
    const float* wkb = wk + pos;
    float acc = 0.f;
    #pragma unroll
    for (int ki = 0; ki < 3; ++ki){
        int hh = h + ki - 1;
        bool hok = (unsigned)hh < 3u;
        #pragma unroll
        for (int kj = 0; kj < 3; ++kj){
            int ww = w + kj - 1;
            bool ok = hok && ((unsigned)ww < 3u);
            float v = ok ? pb[hh * 3 + ww] : 0.f;
            acc += wkb[(size_t)(ki * 3 + kj) * 576] * v;
        }
    }
    out[(size_t)b * C * 9 + c * 9 + hw] = acc;
    float s1 = acc, s2 = acc * acc;
    wave_red2(s1, s2);
    if ((threadIdx.x & 63) == 0){
        atomicAdd(&ostats[c], s1);
        atomicAdd(&ostats[C + c], s2);
    }
}

// ---------------------------------------------------------------------------
// Fused BN+ReLU(+residual) -> conv1x1: out[b,j,hw] = sum_c f(in_c)*w[j,c]
// where f = relu(bn(in_c)) + (idn ? idn_c : 0).
// ---------------------------------------------------------------------------
__global__ void bnconv(const float* __restrict__ in, const float* __restrict__ stats,
                       const float* __restrict__ g, const float* __restrict__ bta,
                       const float* __restrict__ idn, const float* __restrict__ w,
                       float* __restrict__ out, int Cin, int Cout)
{
    __shared__ float sc[204], sh[204];
    for (int j = threadIdx.x; j < Cin; j += 256){
        const float invN = 1.f / 576.f;
        float mean = stats[j] * invN;
        float var = stats[Cin + j] * invN - mean * mean;
        float s = g[j] * rsqrtf(var + EPS);
        sc[j] = s; sh[j] = bta[j] - mean * s;
    }
    __syncthreads();
    int item = blockIdx.x * 256 + threadIdx.x;
    if (item >= Cout * 576) return;
    int j = item / 576, pos = item - j * 576;
    int b = pos / 9, hw = pos - b * 9;
    const float* ip = in + (size_t)b * Cin * 9 + hw;
    const float* ir = idn ? idn + (size_t)b * Cin * 9 + hw : nullptr;
    const float* wr = w + (size_t)j * Cin;
    float acc = 0.f;
    #pragma unroll 4
    for (int c = 0; c < Cin; ++c){
        float v = ip[c * 9] * sc[c] + sh[c];
        v = v > 0.f ? v : 0.f;
        if (ir) v += ir[c * 9];
        acc += v * wr[c];
    }
    out[(size_t)b * Cout * 9 + j * 9 + hw] = acc;
}

// ---------------------------------------------------------------------------
// GlobalCovPooling: one workgroup per batch element, all in LDS. Faithful to
// the reference incl. ELEMENTWISE Y-update in Newton-Schulz.
// ---------------------------------------------------------------------------
template<int C, int N>
__global__ void covpool(const float* __restrict__ in, float* __restrict__ feat)
{
    __shared__ float X[N * C];
    __shared__ float Ybuf[C * C], Mbuf[C * C], Zbuf[C * C], Z2buf[C * C];
    __shared__ float mu[C];
    __shared__ float scal[2];
    int b = blockIdx.x, tid = threadIdx.x;
    const float* ib = in + (size_t)b * C * N;
    for (int i = tid; i < N * C; i += 256){
        int n = i / C, c = i - n * C;
        X[i] = ib[(size_t)c * N + n];
    }
    __syncthreads();
    if (tid < C){
        float s = 0.f;
        #pragma unroll 5
        for (int n = 0; n < N; ++n) s += X[n * C + tid];
        mu[tid] = s / (float)N;
    }
    __syncthreads();
    constexpr int CC = C * C;
    for (int i = tid; i < CC; i += 256){
        int c = i / C, d = i - c * C;
        float s = 0.f;
        #pragma unroll 5
        for (int n = 0; n < N; ++n) s += X[n * C + c] * X[n * C + d];
        Ybuf[i] = s / (float)N - mu[c] * mu[d];
    }
    __syncthreads();
    if (tid == 0){
        float tr = 0.f;
        for (int c = 0; c < C; ++c) tr += Ybuf[c * C + c];
        scal[0] = 1.f / tr;
    }
    __syncthreads();
    for (int i = tid; i < CC; i += 256){
        int c = i / C, d = i - c * C;
        Ybuf[i] *= scal[0];
        Zbuf[i] = (c == d) ? 1.f : 0.f;
    }
    __syncthreads();
    float* zs = Zbuf; float* zd = Z2buf;
    for (int it = 0; it < 6; ++it){
        for (int i = tid; i < CC; i += 256){
            int c = i / C, d = i - c * C;
            float s = 0.f;
            #pragma unroll 6
            for (int e = 0; e < C; ++e) s += zs[c * C + e] * Ybuf[e * C + d];
            Mbuf[i] = ((c == d) ? 3.f : 0.f) - s;
        }
        __syncthreads();
        for (int i = tid; i < CC; i += 256){
            int c = i / C, d = i - c * C;
            float s = 0.f;
            #pragma unroll 6
            for (int e = 0; e < C; ++e) s += Mbuf[c * C + e] * zs[e * C + d];
            zd[i] = 0.5f * s;
        }
        for (int i = tid; i < CC; i += 256) Ybuf[i] *= 0.5f * Mbuf[i];   // elementwise, as in source
        __syncthreads();
        float* t = zs; zs = zd; zd = t;
    }
    if (tid == 0){
        float tr = 0.f;
        for (int c = 0; c < C; ++c) tr += Ybuf[c * C + c];
        scal[1] = sqrtf(tr);
    }
    __syncthreads();
    if (tid < C){
        float s = 0.f;
        #pragma unroll 6
        for (int c = 0; c < C; ++c) s += Ybuf[c * C + tid];
        feat[(size_t)b * C + tid] = scal[1] * s / (float)C;
    }
}

// ---------------------------------------------------------------------------
// Head: concat feats, BN over batch, ReLU, linear, softmax. Single workgroup.
// ---------------------------------------------------------------------------
__global__ void head_k(const float* __restrict__ feat1, const float* __restrict__ feat2,
                       const float* __restrict__ hg, const float* __restrict__ hb,
                       const float* __restrict__ lw, const float* __restrict__ lb,
                       float* __restrict__ out)
{
    __shared__ float f[46 * 64];
    int tid = threadIdx.x;
    for (int i = tid; i < 46 * 64; i += 256){
        int ch = i / 64, b = i - ch * 64;
        f[i] = ch < 30 ? feat1[b * 30 + ch] : feat2[b * 16 + (ch - 30)];
    }
    __syncthreads();
    if (tid < 46){
        float s = 0.f, s2 = 0.f;
        for (int b = 0; b < 64; ++b){ float v = f[tid * 64 + b]; s += v; s2 += v * v; }
        float mean = s / 64.f, var = s2 / 64.f - mean * mean;
        float sc = hg[tid] * rsqrtf(var + EPS), sh = hb[tid] - mean * sc;
        for (int b = 0; b < 64; ++b){
            float v = f[tid * 64 + b] * sc + sh;
            f[tid * 64 + b] = v > 0.f ? v : 0.f;
        }
    }
    __syncthreads();
    if (tid < 64){
        int b = tid;
        float l[16];
        float m = -1e30f;
        for (int o = 0; o < 16; ++o){
            float a = lb[o];
            for (int ch = 0; ch < 46; ++ch) a += f[ch * 64 + b] * lw[o * 46 + ch];
            l[o] = a; m = fmaxf(m, a);
        }
        float se = 0.f;
        for (int o = 0; o < 16; ++o){ l[o] = expf(l[o] - m); se += l[o]; }
        float inv = 1.f / se;
        for (int o = 0; o < 16; ++o) out[b * 16 + o] = l[o] * inv;
    }
}

extern "C" void kernel_launch(void* const* d_in, const int* in_sizes, int n_in,
                              void* d_out, int out_size, void* d_ws, size_t ws_size,
                              hipStream_t stream)
{
    (void)in_sizes; (void)n_in; (void)out_size; (void)ws_size;
    const float* x        = (const float*)d_in[0];
    const float* y        = (const float*)d_in[1];
    const float* blk_w1   = (const float*)d_in[2];
    const float* blk_ig   = (const float*)d_in[3];
    const float* blk_ib   = (const float*)d_in[4];
    const float* blk_w2_5 = (const float*)d_in[5];
    const float* blk_w2_7 = (const float*)d_in[6];
    const float* blk_w2_9 = (const float*)d_in[7];
    const float* blk_g    = (const float*)d_in[8];
    const float* blk_b    = (const float*)d_in[9];
    const float* blk_conv = (const float*)d_in[10];
    const float* loc_w1 = (const float*)d_in[11];
    const float* loc_g  = (const float*)d_in[12];
    const float* loc_b  = (const float*)d_in[13];
    const float* loc_w2 = (const float*)d_in[14];
    const float* glb_w1 = (const float*)d_in[15];
    const float* glb_g  = (const float*)d_in[16];
    const float* glb_b  = (const float*)d_in[17];
    const float* glb_w2 = (const float*)d_in[18];
    const float* c3_w1 = (const float*)d_in[19];
    const float* c3_g  = (const float*)d_in[20];
    const float* c3_b  = (const float*)d_in[21];
    const float* c3_w2 = (const float*)d_in[22];
    const float* c4_w1 = (const float*)d_in[23];
    const float* c4_g  = (const float*)d_in[24];
    const float* c4_b  = (const float*)d_in[25];
    const float* c4_w2 = (const float*)d_in[26];
    const float* c5_w1 = (const float*)d_in[27];
    const float* c5_g  = (const float*)d_in[28];
    const float* c5_b  = (const float*)d_in[29];
    const float* c5_w2 = (const float*)d_in[30];
    const float* p1 = (const float*)d_in[31];
    const float* p2 = (const float*)d_in[32];
    const float* p3 = (const float*)d_in[33];
    const float* bn1g = (const float*)d_in[34];
    const float* bn1b = (const float*)d_in[35];
    const float* bn2g = (const float*)d_in[36];
    const float* bn2b = (const float*)d_in[37];
    const float* bn3g = (const float*)d_in[38];
    const float* bn3b = (const float*)d_in[39];
    const float* hg = (const float*)d_in[40];
    const float* hb = (const float*)d_in[41];
    const float* lw = (const float*)d_in[42];
    const float* lb = (const float*)d_in[43];

    float* ws = (float*)d_ws;
    size_t off = 0;
    auto alloc = [&](size_t n){ float* p = ws + off; off += n; return p; };
    float* bufA    = alloc(432000);
    float* bufB    = alloc(432000);
    float* scratch = alloc(1944000);   // branch1 t_raw(3)+o_raw(3); branch2 aliases this
    float* wkbuf   = alloc(2332800);   // branch-2 dynamic-kernel scratch
    float* feat1   = alloc(64 * 30);
    float* feat2   = alloc(64 * 16);
    float* stats   = alloc(2288);

    float* t_raw = scratch;            // 3 x 216000
    float* o_raw = scratch + 648000;   // 3 x 432000

    hipMemsetAsync(stats, 0, 2288 * sizeof(float), stream);

    const int invol_lds = (3375 + 3375 + 1215 + 30) * sizeof(float);

    // ---- branch 1: 3 IVoubottleneck blocks ----
    const float* cur = x;
    float* dst = bufA;
    for (int bi = 0; bi < 3; ++bi){
        float* st_t = stats + bi * 90;          // 3 x (15 sum + 15 sumsq)
        float* st_o = stats + 270 + bi * 180;   // 3 x (30 sum + 30 sumsq)
        conv1x1_k<<<dim3(844, 1, 3), 256, 0, stream>>>(
            cur, blk_w1 + bi * 1350, t_raw, st_t, 30, 15, 225, 64, 450, 216000, 30);
        invol_b1_all<<<dim3(64, 2, 3), 256, invol_lds, stream>>>(
            cur, t_raw, st_t, blk_ig + bi * 45, blk_ib + bi * 45,
            blk_w2_5 + bi * 750, blk_w2_7 + bi * 1470, blk_w2_9 + bi * 2430,
            o_raw, st_o);
        blockend<<<1688, 256, 0, stream>>>(o_raw, o_raw + 432000, o_raw + 864000,
                                           st_o, st_o + 60, st_o + 120,
                                           blk_g + bi * 90, blk_b + bi * 90, blk_conv + bi * 2700,
                                           cur, dst);
        cur = dst;
        dst = (bi == 0) ? bufB : bufA;
    }
    covpool<30, 225><<<64, 256, 0, stream>>>(cur, feat1);

    // ---- branch 2: cross attention (aliases scratch; branch-1 uses are done) ----
    float* t_loc = scratch;
    float* t_glb = t_loc + 58752;
    float* o_idn = t_glb + 58752;
    float* t3    = o_idn + 117504;
    float* o3    = t3 + 58752;
    float* o5    = o3 + 117504;
    float* t4    = o5 + 58752;
    float* o6    = t4 + 29376;
    float* o8    = o6 + 58752;
    float* t5    = o8 + 29376;
    float* o9    = t5 + 14400;
    float* o11   = o9 + 29376;

    float* wkloc = wkbuf;              // 1836*576
    float* wkglb = wkbuf + 1057536;    // 9*576

    float* s_tloc = stats + 810;
    float* s_tglb = s_tloc + 204;
    float* s_t3   = s_tglb + 204;
    float* s_o3   = s_t3 + 204;
    float* s_t4   = s_o3 + 408;
    float* s_o6   = s_t4 + 102;
    float* s_t5   = s_o6 + 204;
    float* s_o9   = s_t5 + 50;

    conv1x1_k<<<230, 256, 0, stream>>>(y, loc_w1, t_loc, s_tloc, 204, 102, 9, 64, 0, 0, 0);
    conv1x1_k<<<230, 256, 0, stream>>>(y, glb_w1, t_glb, s_tglb, 204, 102, 9, 64, 0, 0, 0);
    invol3_wkgen<<<689, 256, 0, stream>>>(t_loc, s_tloc, loc_g, loc_b, loc_w2, wkloc, 1836, 102);
    invol3_wkgen<<<5, 256, 0, stream>>>(t_glb, s_tglb, glb_g, glb_b, glb_w2, wkglb, 9, 102);
    crossatt_apply<<<459, 256, 0, stream>>>(y, wkloc, wkglb, o_idn);
    // c3
    conv1x1_k<<<230, 256, 0, stream>>>(o_idn, c3_w1, t3, s_t3, 204, 102, 9, 64, 0, 0, 0);
    invol3_wkgen<<<5, 256, 0, stream>>>(t3, s_t3, c3_g, c3_b, c3_w2, wkbuf, 9, 102);
    invol3_apply<<<459, 256, 0, stream>>>(o_idn, wkbuf, o3, s_o3, 204);
    bnconv<<<230, 256, 0, stream>>>(o3, s_o3, bn1g, bn1b, o_idn, p1, o5, 204, 102);
    // c4
    conv1x1_k<<<115, 256, 0, stream>>>(o5, c4_w1, t4, s_t4, 102, 51, 9, 64, 0, 0, 0);
    invol3_wkgen<<<5, 256, 0, stream>>>(t4, s_t4, c4_g, c4_b, c4_w2, wkbuf, 9, 51);
    invol3_apply<<<230, 256, 0, stream>>>(o5, wkbuf, o6, s_o6, 102);
    bnconv<<<115, 256, 0, stream>>>(o6, s_o6, bn2g, bn2b, nullptr, p2, o8, 102, 51);
    // c5
    conv1x1_k<<<57, 256, 0, stream>>>(o8, c5_w1, t5, s_t5, 51, 25, 9, 64, 0, 0, 0);
    invol3_wkgen<<<5, 256, 0, stream>>>(t5, s_t5, c5_g, c5_b, c5_w2, wkbuf, 9, 25);
    invol3_apply<<<115, 256, 0, stream>>>(o8, wkbuf, o9, s_o9, 51);
    bnconv<<<36, 256, 0, stream>>>(o9, s_o9, bn3g, bn3b, o8, p3, o11, 51, 16);
    covpool<16, 9><<<64, 256, 0, stream>>>(o11, feat2);

    // ---- head ----
    head_k<<<1, 256, 0, stream>>>(feat1, feat2, hg, hb, lw, lb, (float*)d_out);
}

// Round 4
// 1399.072 us; speedup vs baseline: 1.5627x; 1.0989x over previous
//
#include <hip/hip_runtime.h>
#include <math.h>

#define EPS 1e-5f

__device__ inline void wave_red2(float& s1, float& s2){
    for (int off = 32; off; off >>= 1){
        s1 += __shfl_down(s1, off, 64);
        s2 += __shfl_down(s2, off, 64);
    }
}

// ---------------------------------------------------------------------------
// Generic conv1x1 (out[b,j,hw] = sum_c in[b,c,hw]*w[j,c]) with optional
// per-channel (sum, sumsq) stats accumulation. grid.z selects weight/out/stats
// slices. Requires total threads to cover full waves per j (npos % 64 == 0).
// ---------------------------------------------------------------------------
__global__ void conv1x1_k(const float* __restrict__ in, const float* __restrict__ w,
                          float* __restrict__ out, float* __restrict__ stats,
                          int Cin, int Cout, int HW, int B,
                          int wStrideZ, int outStrideZ, int statsStrideZ)
{
    const float* wz = w + (size_t)blockIdx.z * wStrideZ;
    float* oz = out + (size_t)blockIdx.z * outStrideZ;
    float* sz = stats ? stats + (size_t)blockIdx.z * statsStrideZ : nullptr;
    int npos = B * HW;
    int total = Cout * npos;
    int item = blockIdx.x * blockDim.x + threadIdx.x;
    if (item >= total) return;
    int j = item / npos;
    int pos = item - j * npos;
    int b = pos / HW, hw = pos - b * HW;
    const float* ip = in + (size_t)b * Cin * HW + hw;
    const float* wr = wz + (size_t)j * Cin;
    float acc = 0.f;
    #pragma unroll 4
    for (int c = 0; c < Cin; ++c) acc += ip[(size_t)c * HW] * wr[c];
    oz[(size_t)b * Cout * HW + (size_t)j * HW + hw] = acc;
    if (sz){
        float s1 = acc, s2 = acc * acc;
        wave_red2(s1, s2);
        if ((threadIdx.x & 63) == 0){
            atomicAdd(&sz[j], s1);
            atomicAdd(&sz[Cout + j], s2);
        }
    }
}

// ---------------------------------------------------------------------------
// Dual conv1x1 for branch-2 (t_loc & t_glb in one launch). HW=9, B=64.
// ---------------------------------------------------------------------------
__global__ void conv_dual(const float* __restrict__ in,
                          const float* __restrict__ wA, const float* __restrict__ wB,
                          float* __restrict__ outA, float* __restrict__ outB,
                          float* __restrict__ stA, float* __restrict__ stB,
                          int Cin, int Cout)
{
    const float* w = blockIdx.z ? wB : wA;
    float* out = blockIdx.z ? outB : outA;
    float* st  = blockIdx.z ? stB : stA;
    int total = Cout * 576;
    int item = blockIdx.x * 256 + threadIdx.x;
    if (item >= total) return;
    int j = item / 576, pos = item - j * 576;
    int b = pos / 9, hw = pos - b * 9;
    const float* ip = in + (size_t)b * Cin * 9 + hw;
    const float* wr = w + (size_t)j * Cin;
    float acc = 0.f;
    #pragma unroll 4
    for (int c = 0; c < Cin; ++c) acc += ip[c * 9] * wr[c];
    out[(size_t)b * Cout * 9 + j * 9 + hw] = acc;
    float s1 = acc, s2 = acc * acc;
    wave_red2(s1, s2);
    if ((threadIdx.x & 63) == 0){
        atomicAdd(&st[j], s1);
        atomicAdd(&st[Cout + j], s2);
    }
}

// ---------------------------------------------------------------------------
// FUSED branch-1 involution v2: block = (b, g, channel-half, ksize).
// Per kernel position kk: wkv computed on the fly from treg[15] (registers)
// and w2 (LDS), immediately FMA'd into acc[8]. No wk array -> no spills.
// t read directly from global (coalesced, L2-resident).
// ---------------------------------------------------------------------------
template<int K>
__device__ void invol_b1_dev(const float* __restrict__ in, const float* __restrict__ t_raw,
                             const float* __restrict__ tstats,
                             const float* __restrict__ tg, const float* __restrict__ tb,
                             const float* __restrict__ w2,
                             float* __restrict__ o_raw, float* __restrict__ ostats,
                             float* lds, int b, int g, int c0, int nch)
{
    constexpr int KK = K * K, P = (K - 1) / 2;
    float* in_s = lds;            // 8*225
    float* w2_s = lds + 1800;     // <= 1215
    float* scb  = lds + 3015;     // 15
    float* shb  = lds + 3030;     // 15
    int tid = threadIdx.x;

    if (tid < 15){
        const float invN = 1.f / 14400.f;
        float mean = tstats[tid] * invN;
        float var  = tstats[15 + tid] * invN - mean * mean;
        float s = tg[tid] * rsqrtf(var + EPS);
        scb[tid] = s; shb[tid] = tb[tid] - mean * s;
    }
    const float* w2g = w2 + (size_t)g * KK * 15;
    for (int i = tid; i < KK * 15; i += 256) w2_s[i] = w2g[i];
    const float* inb = in + (size_t)b * 6750 + (size_t)(g * 15 + c0) * 225;
    int stage = nch * 225;
    for (int i = tid; i < stage; i += 256) in_s[i] = inb[i];
    __syncthreads();

    bool act = tid < 225;
    int p = act ? tid : 224;
    int h = p / 15, w = p - h * 15;

    float treg[15];
    const float* trb = t_raw + (size_t)b * 3375 + p;
    #pragma unroll
    for (int j = 0; j < 15; ++j){
        float v = trb[j * 225] * scb[j] + shb[j];
        treg[j] = v > 0.f ? v : 0.f;
    }

    float acc[8];
    #pragma unroll
    for (int cc = 0; cc < 8; ++cc) acc[cc] = 0.f;

    for (int ki = 0; ki < K; ++ki){
        int hh = h + ki - P;
        bool hok = (unsigned)hh < 15u;
        #pragma unroll
        for (int kj = 0; kj < K; ++kj){
            int ww = w + kj - P;
            bool ok = hok && ((unsigned)ww < 15u);
            int kk = ki * K + kj;
            float wkv = 0.f;
            #pragma unroll
            for (int j = 0; j < 15; ++j) wkv += treg[j] * w2_s[kk * 15 + j];
            float sc2 = ok ? wkv : 0.f;
            int offr = ok ? hh * 15 + ww : 0;
            #pragma unroll
            for (int cc = 0; cc < 8; ++cc) acc[cc] += sc2 * in_s[cc * 225 + offr];
        }
    }

    float* ob = o_raw + (size_t)b * 6750 + (size_t)(g * 15 + c0) * 225;
    for (int cc = 0; cc < nch; ++cc){
        float val = act ? acc[cc] : 0.f;
        if (act) ob[cc * 225 + p] = val;
        float s1 = val, s2 = val * val;
        wave_red2(s1, s2);
        if ((tid & 63) == 0){
            atomicAdd(&ostats[g * 15 + c0 + cc], s1);
            atomicAdd(&ostats[30 + g * 15 + c0 + cc], s2);
        }
    }
}

__global__ void invol_b1_all(const float* __restrict__ in, const float* __restrict__ t_raw3,
                             const float* __restrict__ tstats3,
                             const float* __restrict__ tg3, const float* __restrict__ tb3,
                             const float* __restrict__ w2_5, const float* __restrict__ w2_7,
                             const float* __restrict__ w2_9,
                             float* __restrict__ o_raw3, float* __restrict__ ostats3)
{
    __shared__ float lds[3045];
    int b = blockIdx.x;
    int g = blockIdx.y >> 1;
    int c0 = (blockIdx.y & 1) * 8;
    int nch = c0 ? 7 : 8;
    int ii = blockIdx.z;
    if (ii == 0)
        invol_b1_dev<5>(in, t_raw3,          tstats3,      tg3,      tb3,      w2_5, o_raw3,          ostats3,       lds, b, g, c0, nch);
    else if (ii == 1)
        invol_b1_dev<7>(in, t_raw3 + 216000, tstats3 + 30, tg3 + 15, tb3 + 15, w2_7, o_raw3 + 432000, ostats3 + 60,  lds, b, g, c0, nch);
    else
        invol_b1_dev<9>(in, t_raw3 + 432000, tstats3 + 60, tg3 + 30, tb3 + 30, w2_9, o_raw3 + 864000, ostats3 + 120, lds, b, g, c0, nch);
}

// ---------------------------------------------------------------------------
// Branch-1 block end: out_new = conv1x1(concat(relu(bn(o_ii))), conv) + out_old
// ---------------------------------------------------------------------------
__global__ void blockend(const float* __restrict__ o0, const float* __restrict__ o1,
                         const float* __restrict__ o2,
                         const float* __restrict__ s0, const float* __restrict__ s1,
                         const float* __restrict__ s2,
                         const float* __restrict__ g, const float* __restrict__ bb,
                         const float* __restrict__ conv,
                         const float* __restrict__ oldout, float* __restrict__ newout)
{
    __shared__ float sc[90], sh[90];
    int tid = threadIdx.x;
    if (tid < 90){
        int ii = tid / 30, cc = tid - ii * 30;
        const float* st = ii == 0 ? s0 : (ii == 1 ? s1 : s2);
        const float invN = 1.f / 14400.f;
        float mean = st[cc] * invN;
        float var = st[30 + cc] * invN - mean * mean;
        float s = g[tid] * rsqrtf(var + EPS);
        sc[tid] = s; sh[tid] = bb[tid] - mean * s;
    }
    __syncthreads();
    int item = blockIdx.x * 256 + tid;
    if (item >= 432000) return;
    int c = item / 14400, pos = item - c * 14400;
    int b = pos / 225, hw = pos - b * 225;
    float acc = oldout[(size_t)b * 6750 + c * 225 + hw];
    const float* cr = conv + c * 90;
    const float* bases[3] = {o0, o1, o2};
    #pragma unroll
    for (int ii = 0; ii < 3; ++ii){
        const float* op = bases[ii] + (size_t)b * 6750 + hw;
        #pragma unroll 6
        for (int cc = 0; cc < 30; ++cc){
            float v = op[cc * 225] * sc[ii * 30 + cc] + sh[ii * 30 + cc];
            v = v > 0.f ? v : 0.f;
            acc += v * cr[ii * 30 + cc];
        }
    }
    newout[(size_t)b * 6750 + c * 225 + hw] = acc;
}

// ---------------------------------------------------------------------------
// Fused cross-attention front: o = y * (loc(y) + glb(y)). Each thread computes
// its own wkl[9] (per-channel loc rows, wave-uniform w2 reads since 576%64==0)
// and wkg[9], combined into one window pass.
// ---------------------------------------------------------------------------
__global__ void crossatt_fused(const float* __restrict__ y,
                               const float* __restrict__ t_loc, const float* __restrict__ t_glb,
                               const float* __restrict__ s_tloc, const float* __restrict__ s_tglb,
                               const float* __restrict__ lg, const float* __restrict__ lb,
                               const float* __restrict__ gg, const float* __restrict__ gb,
                               const float* __restrict__ loc_w2, const float* __restrict__ glb_w2,
                               float* __restrict__ out)
{
    __shared__ float lsc[102], lsh[102], gsc[102], gsh[102];
    const float invN = 1.f / 576.f;
    for (int j = threadIdx.x; j < 102; j += 256){
        float m1 = s_tloc[j] * invN;
        float v1 = s_tloc[102 + j] * invN - m1 * m1;
        float a1 = lg[j] * rsqrtf(v1 + EPS);
        lsc[j] = a1; lsh[j] = lb[j] - m1 * a1;
        float m2 = s_tglb[j] * invN;
        float v2 = s_tglb[102 + j] * invN - m2 * m2;
        float a2 = gg[j] * rsqrtf(v2 + EPS);
        gsc[j] = a2; gsh[j] = gb[j] - m2 * a2;
    }
    __syncthreads();
    int item = blockIdx.x * 256 + threadIdx.x;
    if (item >= 204 * 576) return;
    int c = item / 576, pos = item - c * 576;
    int b = pos / 9, hw = pos - b * 9;
    int h = hw / 3, w = hw - h * 3;

    const float* tl = t_loc + (size_t)b * 918 + hw;
    const float* tg_ = t_glb + (size_t)b * 918 + hw;
    const float* wl = loc_w2 + (size_t)c * 918;   // rows c*9+kk, each 102 wide
    float wk[9];
    #pragma unroll
    for (int kk = 0; kk < 9; ++kk) wk[kk] = 0.f;
    for (int j = 0; j < 102; ++j){
        float a = tl[j * 9] * lsc[j] + lsh[j];
        a = a > 0.f ? a : 0.f;
        float g2 = tg_[j * 9] * gsc[j] + gsh[j];
        g2 = g2 > 0.f ? g2 : 0.f;
        #pragma unroll
        for (int kk = 0; kk < 9; ++kk)
            wk[kk] += a * wl[kk * 102 + j] + g2 * glb_w2[kk * 102 + j];
    }
    const float* pb = y + (size_t)b * 1836 + c * 9;
    float acc = 0.f;
    #pragma unroll
    for (int ki = 0; ki < 3; ++ki){
        int hh = h + ki - 1;
        bool hok = (unsigned)hh < 3u;
        #pragma unroll
        for (int kj = 0; kj < 3; ++kj){
            int ww = w + kj - 1;
            bool ok = hok && ((unsigned)ww < 3u);
            float v = ok ? pb[hh * 3 + ww] : 0.f;
            acc += wk[ki * 3 + kj] * v;
        }
    }
    out[(size_t)b * 1836 + c * 9 + hw] = pb[hw] * acc;
}

// ---------------------------------------------------------------------------
// Fused groups==1 involution (wkgen + apply + stats) for c3/c4/c5.
// Each thread recomputes wk[9] (cheap; w2 in LDS) then applies the window.
// ---------------------------------------------------------------------------
__global__ void invol3_fused(const float* __restrict__ pin, const float* __restrict__ t_raw,
                             const float* __restrict__ tstats,
                             const float* __restrict__ tg, const float* __restrict__ tb,
                             const float* __restrict__ w2,
                             float* __restrict__ out, float* __restrict__ ostats,
                             int C, int Ct)
{
    __shared__ float tsc[102], tsh[102], w2s[918];
    const float invN = 1.f / 576.f;
    for (int j = threadIdx.x; j < Ct; j += 256){
        float mean = tstats[j] * invN;
        float var  = tstats[Ct + j] * invN - mean * mean;
        float s = tg[j] * rsqrtf(var + EPS);
        tsc[j] = s; tsh[j] = tb[j] - mean * s;
    }
    for (int i = threadIdx.x; i < 9 * Ct; i += 256) w2s[i] = w2[i];
    __syncthreads();
    int item = blockIdx.x * 256 + threadIdx.x;
    if (item >= C * 576) return;
    int c = item / 576, pos = item - c * 576;
    int b = pos / 9, hw = pos - b * 9;
    int h = hw / 3, w = hw - h * 3;

    const float* tp = t_raw + (size_t)b * Ct * 9 + hw;
    float wk[9];
    #pragma unroll
    for (int kk = 0; kk < 9; ++kk) wk[kk] = 0.f;
    for (int j = 0; j < Ct; ++j){
        float t = tp[j * 9] * tsc[j] + tsh[j];
        t = t > 0.f ? t : 0.f;
        #pragma unroll
        for (int kk = 0; kk < 9; ++kk) wk[kk] += t * w2s[kk * Ct + j];
    }
    const float* pb = pin + (size_t)b * C * 9 + c * 9;
    float acc = 0.f;
    #pragma unroll
    for (int ki = 0; ki < 3; ++ki){
        int hh = h + ki - 1;
        bool hok = (unsigned)hh < 3u;
        #pragma unroll
        for (int kj = 0; kj < 3; ++kj){
            int ww = w + kj - 1;
            bool ok = hok && ((unsigned)ww < 3u);
            float v = ok ? pb[hh * 3 + ww] : 0.f;
            acc += wk[ki * 3 + kj] * v;
        }
    }
    out[(size_t)b * C * 9 + c * 9 + hw] = acc;
    float s1 = acc, s2 = acc * acc;
    wave_red2(s1, s2);
    if ((threadIdx.x & 63) == 0){
        atomicAdd(&ostats[c], s1);
        atomicAdd(&ostats[C + c], s2);
    }
}

// ---------------------------------------------------------------------------
// Fused BN+ReLU(+residual) -> conv1x1
// ---------------------------------------------------------------------------
__global__ void bnconv(const float* __restrict__ in, const float* __restrict__ stats,
                       const float* __restrict__ g, const float* __restrict__ bta,
                       const float* __restrict__ idn, const float* __restrict__ w,
                       float* __restrict__ out, int Cin, int Cout)
{
    __shared__ float sc[204], sh[204];
    for (int j = threadIdx.x; j < Cin; j += 256){
        const float invN = 1.f / 576.f;
        float mean = stats[j] * invN;
        float var = stats[Cin + j] * invN - mean * mean;
        float s = g[j] * rsqrtf(var + EPS);
        sc[j] = s; sh[j] = bta[j] - mean * s;
    }
    __syncthreads();
    int item = blockIdx.x * 256 + threadIdx.x;
    if (item >= Cout * 576) return;
    int j = item / 576, pos = item - j * 576;
    int b = pos / 9, hw = pos - b * 9;
    const float* ip = in + (size_t)b * Cin * 9 + hw;
    const float* ir = idn ? idn + (size_t)b * Cin * 9 + hw : nullptr;
    const float* wr = w + (size_t)j * Cin;
    float acc = 0.f;
    #pragma unroll 4
    for (int c = 0; c < Cin; ++c){
        float v = ip[c * 9] * sc[c] + sh[c];
        v = v > 0.f ? v : 0.f;
        if (ir) v += ir[c * 9];
        acc += v * wr[c];
    }
    out[(size_t)b * Cout * 9 + j * 9 + hw] = acc;
}

// ---------------------------------------------------------------------------
// GlobalCovPooling: one workgroup per batch element, all in LDS. Faithful to
// the reference incl. ELEMENTWISE Y-update in Newton-Schulz. blockDim-agnostic.
// ---------------------------------------------------------------------------
template<int C, int N>
__global__ void covpool(const float* __restrict__ in, float* __restrict__ feat)
{
    __shared__ float X[N * C];
    __shared__ float Ybuf[C * C], Mbuf[C * C], Zbuf[C * C], Z2buf[C * C];
    __shared__ float mu[C];
    __shared__ float scal[2];
    int b = blockIdx.x, tid = threadIdx.x, bd = blockDim.x;
    const float* ib = in + (size_t)b * C * N;
    for (int i = tid; i < N * C; i += bd){
        int n = i / C, c = i - n * C;
        X[i] = ib[(size_t)c * N + n];
    }
    __syncthreads();
    if (tid < C){
        float s = 0.f;
        #pragma unroll 5
        for (int n = 0; n < N; ++n) s += X[n * C + tid];
        mu[tid] = s / (float)N;
    }
    __syncthreads();
    constexpr int CC = C * C;
    for (int i = tid; i < CC; i += bd){
        int c = i / C, d = i - c * C;
        float s = 0.f;
        #pragma unroll 5
        for (int n = 0; n < N; ++n) s += X[n * C + c] * X[n * C + d];
        Ybuf[i] = s / (float)N - mu[c] * mu[d];
    }
    __syncthreads();
    if (tid == 0){
        float tr = 0.f;
        for (int c = 0; c < C; ++c) tr += Ybuf[c * C + c];
        scal[0] = 1.f / tr;
    }
    __syncthreads();
    for (int i = tid; i < CC; i += bd){
        int c = i / C, d = i - c * C;
        Ybuf[i] *= scal[0];
        Zbuf[i] = (c == d) ? 1.f : 0.f;
    }
    __syncthreads();
    float* zs = Zbuf; float* zd = Z2buf;
    for (int it = 0; it < 6; ++it){
        for (int i = tid; i < CC; i += bd){
            int c = i / C, d = i - c * C;
            float s = 0.f;
            #pragma unroll 6
            for (int e = 0; e < C; ++e) s += zs[c * C + e] * Ybuf[e * C + d];
            Mbuf[i] = ((c == d) ? 3.f : 0.f) - s;
        }
        __syncthreads();
        for (int i = tid; i < CC; i += bd){
            int c = i / C, d = i - c * C;
            float s = 0.f;
            #pragma unroll 6
            for (int e = 0; e < C; ++e) s += Mbuf[c * C + e] * zs[e * C + d];
            zd[i] = 0.5f * s;
        }
        for (int i = tid; i < CC; i += bd) Ybuf[i] *= 0.5f * Mbuf[i];   // elementwise, as in source
        __syncthreads();
        float* t = zs; zs = zd; zd = t;
    }
    if (tid == 0){
        float tr = 0.f;
        for (int c = 0; c < C; ++c) tr += Ybuf[c * C + c];
        scal[1] = sqrtf(tr);
    }
    __syncthreads();
    if (tid < C){
        float s = 0.f;
        #pragma unroll 6
        for (int c = 0; c < C; ++c) s += Ybuf[c * C + tid];
        feat[(size_t)b * C + tid] = scal[1] * s / (float)C;
    }
}

// ---------------------------------------------------------------------------
// Head: concat feats, BN over batch, ReLU, linear, softmax. Single workgroup.
// ---------------------------------------------------------------------------
__global__ void head_k(const float* __restrict__ feat1, const float* __restrict__ feat2,
                       const float* __restrict__ hg, const float* __restrict__ hb,
                       const float* __restrict__ lw, const float* __restrict__ lb,
                       float* __restrict__ out)
{
    __shared__ float f[46 * 64];
    int tid = threadIdx.x;
    for (int i = tid; i < 46 * 64; i += 256){
        int ch = i / 64, b = i - ch * 64;
        f[i] = ch < 30 ? feat1[b * 30 + ch] : feat2[b * 16 + (ch - 30)];
    }
    __syncthreads();
    if (tid < 46){
        float s = 0.f, s2 = 0.f;
        for (int b = 0; b < 64; ++b){ float v = f[tid * 64 + b]; s += v; s2 += v * v; }
        float mean = s / 64.f, var = s2 / 64.f - mean * mean;
        float sc = hg[tid] * rsqrtf(var + EPS), sh = hb[tid] - mean * sc;
        for (int b = 0; b < 64; ++b){
            float v = f[tid * 64 + b] * sc + sh;
            f[tid * 64 + b] = v > 0.f ? v : 0.f;
        }
    }
    __syncthreads();
    if (tid < 64){
        int b = tid;
        float l[16];
        float m = -1e30f;
        for (int o = 0; o < 16; ++o){
            float a = lb[o];
            for (int ch = 0; ch < 46; ++ch) a += f[ch * 64 + b] * lw[o * 46 + ch];
            l[o] = a; m = fmaxf(m, a);
        }
        float se = 0.f;
        for (int o = 0; o < 16; ++o){ l[o] = expf(l[o] - m); se += l[o]; }
        float inv = 1.f / se;
        for (int o = 0; o < 16; ++o) out[b * 16 + o] = l[o] * inv;
    }
}

extern "C" void kernel_launch(void* const* d_in, const int* in_sizes, int n_in,
                              void* d_out, int out_size, void* d_ws, size_t ws_size,
                              hipStream_t stream)
{
    (void)in_sizes; (void)n_in; (void)out_size; (void)ws_size;
    const float* x        = (const float*)d_in[0];
    const float* y        = (const float*)d_in[1];
    const float* blk_w1   = (const float*)d_in[2];
    const float* blk_ig   = (const float*)d_in[3];
    const float* blk_ib   = (const float*)d_in[4];
    const float* blk_w2_5 = (const float*)d_in[5];
    const float* blk_w2_7 = (const float*)d_in[6];
    const float* blk_w2_9 = (const float*)d_in[7];
    const float* blk_g    = (const float*)d_in[8];
    const float* blk_b    = (const float*)d_in[9];
    const float* blk_conv = (const float*)d_in[10];
    const float* loc_w1 = (const float*)d_in[11];
    const float* loc_g  = (const float*)d_in[12];
    const float* loc_b  = (const float*)d_in[13];
    const float* loc_w2 = (const float*)d_in[14];
    const float* glb_w1 = (const float*)d_in[15];
    const float* glb_g  = (const float*)d_in[16];
    const float* glb_b  = (const float*)d_in[17];
    const float* glb_w2 = (const float*)d_in[18];
    const float* c3_w1 = (const float*)d_in[19];
    const float* c3_g  = (const float*)d_in[20];
    const float* c3_b  = (const float*)d_in[21];
    const float* c3_w2 = (const float*)d_in[22];
    const float* c4_w1 = (const float*)d_in[23];
    const float* c4_g  = (const float*)d_in[24];
    const float* c4_b  = (const float*)d_in[25];
    const float* c4_w2 = (const float*)d_in[26];
    const float* c5_w1 = (const float*)d_in[27];
    const float* c5_g  = (const float*)d_in[28];
    const float* c5_b  = (const float*)d_in[29];
    const float* c5_w2 = (const float*)d_in[30];
    const float* p1 = (const float*)d_in[31];
    const float* p2 = (const float*)d_in[32];
    const float* p3 = (const float*)d_in[33];
    const float* bn1g = (const float*)d_in[34];
    const float* bn1b = (const float*)d_in[35];
    const float* bn2g = (const float*)d_in[36];
    const float* bn2b = (const float*)d_in[37];
    const float* bn3g = (const float*)d_in[38];
    const float* bn3b = (const float*)d_in[39];
    const float* hg = (const float*)d_in[40];
    const float* hb = (const float*)d_in[41];
    const float* lw = (const float*)d_in[42];
    const float* lb = (const float*)d_in[43];

    float* ws = (float*)d_ws;
    size_t off = 0;
    auto alloc = [&](size_t n){ float* p = ws + off; off += n; return p; };
    float* bufA    = alloc(432000);
    float* bufB    = alloc(432000);
    float* scratch = alloc(1944000);   // branch1 t_raw(3)+o_raw(3); branch2 aliases this
    float* feat1   = alloc(64 * 30);
    float* feat2   = alloc(64 * 16);
    float* stats   = alloc(2288);

    float* t_raw = scratch;            // 3 x 216000
    float* o_raw = scratch + 648000;   // 3 x 432000

    hipMemsetAsync(stats, 0, 2288 * sizeof(float), stream);

    // ---- branch 1: 3 IVoubottleneck blocks ----
    const float* cur = x;
    float* dst = bufA;
    for (int bi = 0; bi < 3; ++bi){
        float* st_t = stats + bi * 90;          // 3 x (15 sum + 15 sumsq)
        float* st_o = stats + 270 + bi * 180;   // 3 x (30 sum + 30 sumsq)
        conv1x1_k<<<dim3(844, 1, 3), 256, 0, stream>>>(
            cur, blk_w1 + bi * 1350, t_raw, st_t, 30, 15, 225, 64, 450, 216000, 30);
        invol_b1_all<<<dim3(64, 4, 3), 256, 0, stream>>>(
            cur, t_raw, st_t, blk_ig + bi * 45, blk_ib + bi * 45,
            blk_w2_5 + bi * 750, blk_w2_7 + bi * 1470, blk_w2_9 + bi * 2430,
            o_raw, st_o);
        blockend<<<1688, 256, 0, stream>>>(o_raw, o_raw + 432000, o_raw + 864000,
                                           st_o, st_o + 60, st_o + 120,
                                           blk_g + bi * 90, blk_b + bi * 90, blk_conv + bi * 2700,
                                           cur, dst);
        cur = dst;
        dst = (bi == 0) ? bufB : bufA;
    }
    covpool<30, 225><<<64, 1024, 0, stream>>>(cur, feat1);

    // ---- branch 2: cross attention (aliases scratch; branch-1 uses are done) ----
    float* t_loc = scratch;
    float* t_glb = t_loc + 58752;
    float* o_idn = t_glb + 58752;
    float* t3    = o_idn + 117504;
    float* o3    = t3 + 58752;
    float* o5    = o3 + 117504;
    float* t4    = o5 + 58752;
    float* o6    = t4 + 29376;
    float* o8    = o6 + 58752;
    float* t5    = o8 + 29376;
    float* o9    = t5 + 14400;
    float* o11   = o9 + 29376;

    float* s_tloc = stats + 810;
    float* s_tglb = s_tloc + 204;
    float* s_t3   = s_tglb + 204;
    float* s_o3   = s_t3 + 204;
    float* s_t4   = s_o3 + 408;
    float* s_o6   = s_t4 + 102;
    float* s_t5   = s_o6 + 204;
    float* s_o9   = s_t5 + 50;

    conv_dual<<<dim3(230, 1, 2), 256, 0, stream>>>(y, loc_w1, glb_w1, t_loc, t_glb,
                                                   s_tloc, s_tglb, 204, 102);
    crossatt_fused<<<459, 256, 0, stream>>>(y, t_loc, t_glb, s_tloc, s_tglb,
                                            loc_g, loc_b, glb_g, glb_b,
                                            loc_w2, glb_w2, o_idn);
    // c3
    conv1x1_k<<<230, 256, 0, stream>>>(o_idn, c3_w1, t3, s_t3, 204, 102, 9, 64, 0, 0, 0);
    invol3_fused<<<459, 256, 0, stream>>>(o_idn, t3, s_t3, c3_g, c3_b, c3_w2, o3, s_o3, 204, 102);
    bnconv<<<230, 256, 0, stream>>>(o3, s_o3, bn1g, bn1b, o_idn, p1, o5, 204, 102);
    // c4
    conv1x1_k<<<115, 256, 0, stream>>>(o5, c4_w1, t4, s_t4, 102, 51, 9, 64, 0, 0, 0);
    invol3_fused<<<230, 256, 0, stream>>>(o5, t4, s_t4, c4_g, c4_b, c4_w2, o6, s_o6, 102, 51);
    bnconv<<<115, 256, 0, stream>>>(o6, s_o6, bn2g, bn2b, nullptr, p2, o8, 102, 51);
    // c5
    conv1x1_k<<<57, 256, 0, stream>>>(o8, c5_w1, t5, s_t5, 51, 25, 9, 64, 0, 0, 0);
    invol3_fused<<<115, 256, 0, stream>>>(o8, t5, s_t5, c5_g, c5_b, c5_w2, o9, s_o9, 51, 25);
    bnconv<<<36, 256, 0, stream>>>(o9, s_o9, bn3g, bn3b, o8, p3, o11, 51, 16);
    covpool<16, 9><<<64, 256, 0, stream>>>(o11, feat2);

    // ---- head ----
    head_k<<<1, 256, 0, stream>>>(feat1, feat2, hg, hb, lw, lb, (float*)d_out);
}

// Round 5
// 1313.594 us; speedup vs baseline: 1.6643x; 1.0651x over previous
//
#include <hip/hip_runtime.h>
#include <math.h>

#define EPS 1e-5f

__device__ inline void wave_red2(float& s1, float& s2){
    for (int off = 32; off; off >>= 1){
        s1 += __shfl_down(s1, off, 64);
        s2 += __shfl_down(s2, off, 64);
    }
}

// ---------------------------------------------------------------------------
// Generic conv1x1 (out[b,j,hw] = sum_c in[b,c,hw]*w[j,c]) with optional
// per-channel (sum, sumsq) stats accumulation. grid.z selects weight/out/stats
// slices.
// ---------------------------------------------------------------------------
__global__ __launch_bounds__(256)
void conv1x1_k(const float* __restrict__ in, const float* __restrict__ w,
               float* __restrict__ out, float* __restrict__ stats,
               int Cin, int Cout, int HW, int B,
               int wStrideZ, int outStrideZ, int statsStrideZ)
{
    const float* wz = w + (size_t)blockIdx.z * wStrideZ;
    float* oz = out + (size_t)blockIdx.z * outStrideZ;
    float* sz = stats ? stats + (size_t)blockIdx.z * statsStrideZ : nullptr;
    int npos = B * HW;
    int total = Cout * npos;
    int item = blockIdx.x * blockDim.x + threadIdx.x;
    if (item >= total) return;
    int j = item / npos;
    int pos = item - j * npos;
    int b = pos / HW, hw = pos - b * HW;
    const float* ip = in + (size_t)b * Cin * HW + hw;
    const float* wr = wz + (size_t)j * Cin;
    float acc = 0.f;
    #pragma unroll 4
    for (int c = 0; c < Cin; ++c) acc += ip[(size_t)c * HW] * wr[c];
    oz[(size_t)b * Cout * HW + (size_t)j * HW + hw] = acc;
    if (sz){
        float s1 = acc, s2 = acc * acc;
        wave_red2(s1, s2);
        if ((threadIdx.x & 63) == 0){
            atomicAdd(&sz[j], s1);
            atomicAdd(&sz[Cout + j], s2);
        }
    }
}

// ---------------------------------------------------------------------------
// Dual conv1x1 for branch-2 (t_loc & t_glb in one launch). HW=9, B=64.
// ---------------------------------------------------------------------------
__global__ __launch_bounds__(256)
void conv_dual(const float* __restrict__ in,
               const float* __restrict__ wA, const float* __restrict__ wB,
               float* __restrict__ outA, float* __restrict__ outB,
               float* __restrict__ stA, float* __restrict__ stB,
               int Cin, int Cout)
{
    const float* w = blockIdx.z ? wB : wA;
    float* out = blockIdx.z ? outB : outA;
    float* st  = blockIdx.z ? stB : stA;
    int total = Cout * 576;
    int item = blockIdx.x * 256 + threadIdx.x;
    if (item >= total) return;
    int j = item / 576, pos = item - j * 576;
    int b = pos / 9, hw = pos - b * 9;
    const float* ip = in + (size_t)b * Cin * 9 + hw;
    const float* wr = w + (size_t)j * Cin;
    float acc = 0.f;
    #pragma unroll 4
    for (int c = 0; c < Cin; ++c) acc += ip[c * 9] * wr[c];
    out[(size_t)b * Cout * 9 + j * 9 + hw] = acc;
    float s1 = acc, s2 = acc * acc;
    wave_red2(s1, s2);
    if ((threadIdx.x & 63) == 0){
        atomicAdd(&st[j], s1);
        atomicAdd(&st[Cout + j], s2);
    }
}

// ---------------------------------------------------------------------------
// FUSED branch-1 involution: block = (b, g, channel-half, ksize).
// Per kernel position kk: wkv computed on the fly from treg[15] (registers)
// and w2 (LDS), immediately FMA'd into acc[8]. With launch_bounds(256) the
// whole working set fits in VGPRs (no spills).
// ---------------------------------------------------------------------------
template<int K>
__device__ void invol_b1_dev(const float* __restrict__ in, const float* __restrict__ t_raw,
                             const float* __restrict__ tstats,
                             const float* __restrict__ tg, const float* __restrict__ tb,
                             const float* __restrict__ w2,
                             float* __restrict__ o_raw, float* __restrict__ ostats,
                             float* lds, int b, int g, int c0, int nch)
{
    constexpr int KK = K * K, P = (K - 1) / 2;
    float* in_s = lds;            // 8*225
    float* w2_s = lds + 1800;     // <= 1215
    float* scb  = lds + 3015;     // 15
    float* shb  = lds + 3030;     // 15
    int tid = threadIdx.x;

    if (tid < 15){
        const float invN = 1.f / 14400.f;
        float mean = tstats[tid] * invN;
        float var  = tstats[15 + tid] * invN - mean * mean;
        float s = tg[tid] * rsqrtf(var + EPS);
        scb[tid] = s; shb[tid] = tb[tid] - mean * s;
    }
    const float* w2g = w2 + (size_t)g * KK * 15;
    for (int i = tid; i < KK * 15; i += 256) w2_s[i] = w2g[i];
    const float* inb = in + (size_t)b * 6750 + (size_t)(g * 15 + c0) * 225;
    int stage = nch * 225;
    for (int i = tid; i < stage; i += 256) in_s[i] = inb[i];
    __syncthreads();

    bool act = tid < 225;
    int p = act ? tid : 224;
    int h = p / 15, w = p - h * 15;

    float treg[15];
    const float* trb = t_raw + (size_t)b * 3375 + p;
    #pragma unroll
    for (int j = 0; j < 15; ++j){
        float v = trb[j * 225] * scb[j] + shb[j];
        treg[j] = v > 0.f ? v : 0.f;
    }

    float acc[8];
    #pragma unroll
    for (int cc = 0; cc < 8; ++cc) acc[cc] = 0.f;

    for (int ki = 0; ki < K; ++ki){
        int hh = h + ki - P;
        bool hok = (unsigned)hh < 15u;
        #pragma unroll
        for (int kj = 0; kj < K; ++kj){
            int ww = w + kj - P;
            bool ok = hok && ((unsigned)ww < 15u);
            int kk = ki * K + kj;
            float wkv = 0.f;
            #pragma unroll
            for (int j = 0; j < 15; ++j) wkv += treg[j] * w2_s[kk * 15 + j];
            float sc2 = ok ? wkv : 0.f;
            int offr = ok ? hh * 15 + ww : 0;
            #pragma unroll
            for (int cc = 0; cc < 8; ++cc) acc[cc] += sc2 * in_s[cc * 225 + offr];
        }
    }

    float* ob = o_raw + (size_t)b * 6750 + (size_t)(g * 15 + c0) * 225;
    for (int cc = 0; cc < nch; ++cc){
        float val = act ? acc[cc] : 0.f;
        if (act) ob[cc * 225 + p] = val;
        float s1 = val, s2 = val * val;
        wave_red2(s1, s2);
        if ((tid & 63) == 0){
            atomicAdd(&ostats[g * 15 + c0 + cc], s1);
            atomicAdd(&ostats[30 + g * 15 + c0 + cc], s2);
        }
    }
}

__global__ __launch_bounds__(256)
void invol_b1_all(const float* __restrict__ in, const float* __restrict__ t_raw3,
                  const float* __restrict__ tstats3,
                  const float* __restrict__ tg3, const float* __restrict__ tb3,
                  const float* __restrict__ w2_5, const float* __restrict__ w2_7,
                  const float* __restrict__ w2_9,
                  float* __restrict__ o_raw3, float* __restrict__ ostats3)
{
    __shared__ float lds[3045];
    int b = blockIdx.x;
    int g = blockIdx.y >> 1;
    int c0 = (blockIdx.y & 1) * 8;
    int nch = c0 ? 7 : 8;
    int ii = blockIdx.z;
    if (ii == 0)
        invol_b1_dev<5>(in, t_raw3,          tstats3,      tg3,      tb3,      w2_5, o_raw3,          ostats3,       lds, b, g, c0, nch);
    else if (ii == 1)
        invol_b1_dev<7>(in, t_raw3 + 216000, tstats3 + 30, tg3 + 15, tb3 + 15, w2_7, o_raw3 + 432000, ostats3 + 60,  lds, b, g, c0, nch);
    else
        invol_b1_dev<9>(in, t_raw3 + 432000, tstats3 + 60, tg3 + 30, tb3 + 30, w2_9, o_raw3 + 864000, ostats3 + 120, lds, b, g, c0, nch);
}

// ---------------------------------------------------------------------------
// Branch-1 block end: out_new = conv1x1(concat(relu(bn(o_ii))), conv) + out_old
// ---------------------------------------------------------------------------
__global__ __launch_bounds__(256)
void blockend(const float* __restrict__ o0, const float* __restrict__ o1,
              const float* __restrict__ o2,
              const float* __restrict__ s0, const float* __restrict__ s1,
              const float* __restrict__ s2,
              const float* __restrict__ g, const float* __restrict__ bb,
              const float* __restrict__ conv,
              const float* __restrict__ oldout, float* __restrict__ newout)
{
    __shared__ float sc[90], sh[90];
    int tid = threadIdx.x;
    if (tid < 90){
        int ii = tid / 30, cc = tid - ii * 30;
        const float* st = ii == 0 ? s0 : (ii == 1 ? s1 : s2);
        const float invN = 1.f / 14400.f;
        float mean = st[cc] * invN;
        float var = st[30 + cc] * invN - mean * mean;
        float s = g[tid] * rsqrtf(var + EPS);
        sc[tid] = s; sh[tid] = bb[tid] - mean * s;
    }
    __syncthreads();
    int item = blockIdx.x * 256 + tid;
    if (item >= 432000) return;
    int c = item / 14400, pos = item - c * 14400;
    int b = pos / 225, hw = pos - b * 225;
    float acc = oldout[(size_t)b * 6750 + c * 225 + hw];
    const float* cr = conv + c * 90;
    const float* bases[3] = {o0, o1, o2};
    #pragma unroll
    for (int ii = 0; ii < 3; ++ii){
        const float* op = bases[ii] + (size_t)b * 6750 + hw;
        #pragma unroll 6
        for (int cc = 0; cc < 30; ++cc){
            float v = op[cc * 225] * sc[ii * 30 + cc] + sh[ii * 30 + cc];
            v = v > 0.f ? v : 0.f;
            acc += v * cr[ii * 30 + cc];
        }
    }
    newout[(size_t)b * 6750 + c * 225 + hw] = acc;
}

// ---------------------------------------------------------------------------
// Fused cross-attention front: o = y * (loc(y) + glb(y)).
// ---------------------------------------------------------------------------
__global__ __launch_bounds__(256)
void crossatt_fused(const float* __restrict__ y,
                    const float* __restrict__ t_loc, const float* __restrict__ t_glb,
                    const float* __restrict__ s_tloc, const float* __restrict__ s_tglb,
                    const float* __restrict__ lg, const float* __restrict__ lb,
                    const float* __restrict__ gg, const float* __restrict__ gb,
                    const float* __restrict__ loc_w2, const float* __restrict__ glb_w2,
                    float* __restrict__ out)
{
    __shared__ float lsc[102], lsh[102], gsc[102], gsh[102];
    const float invN = 1.f / 576.f;
    for (int j = threadIdx.x; j < 102; j += 256){
        float m1 = s_tloc[j] * invN;
        float v1 = s_tloc[102 + j] * invN - m1 * m1;
        float a1 = lg[j] * rsqrtf(v1 + EPS);
        lsc[j] = a1; lsh[j] = lb[j] - m1 * a1;
        float m2 = s_tglb[j] * invN;
        float v2 = s_tglb[102 + j] * invN - m2 * m2;
        float a2 = gg[j] * rsqrtf(v2 + EPS);
        gsc[j] = a2; gsh[j] = gb[j] - m2 * a2;
    }
    __syncthreads();
    int item = blockIdx.x * 256 + threadIdx.x;
    if (item >= 204 * 576) return;
    int c = item / 576, pos = item - c * 576;
    int b = pos / 9, hw = pos - b * 9;
    int h = hw / 3, w = hw - h * 3;

    const float* tl = t_loc + (size_t)b * 918 + hw;
    const float* tg_ = t_glb + (size_t)b * 918 + hw;
    const float* wl = loc_w2 + (size_t)c * 918;
    float wk[9];
    #pragma unroll
    for (int kk = 0; kk < 9; ++kk) wk[kk] = 0.f;
    for (int j = 0; j < 102; ++j){
        float a = tl[j * 9] * lsc[j] + lsh[j];
        a = a > 0.f ? a : 0.f;
        float g2 = tg_[j * 9] * gsc[j] + gsh[j];
        g2 = g2 > 0.f ? g2 : 0.f;
        #pragma unroll
        for (int kk = 0; kk < 9; ++kk)
            wk[kk] += a * wl[kk * 102 + j] + g2 * glb_w2[kk * 102 + j];
    }
    const float* pb = y + (size_t)b * 1836 + c * 9;
    float acc = 0.f;
    #pragma unroll
    for (int ki = 0; ki < 3; ++ki){
        int hh = h + ki - 1;
        bool hok = (unsigned)hh < 3u;
        #pragma unroll
        for (int kj = 0; kj < 3; ++kj){
            int ww = w + kj - 1;
            bool ok = hok && ((unsigned)ww < 3u);
            float v = ok ? pb[hh * 3 + ww] : 0.f;
            acc += wk[ki * 3 + kj] * v;
        }
    }
    out[(size_t)b * 1836 + c * 9 + hw] = pb[hw] * acc;
}

// ---------------------------------------------------------------------------
// Fused groups==1 involution (wkgen + apply + stats) for c3/c4/c5.
// ---------------------------------------------------------------------------
__global__ __launch_bounds__(256)
void invol3_fused(const float* __restrict__ pin, const float* __restrict__ t_raw,
                  const float* __restrict__ tstats,
                  const float* __restrict__ tg, const float* __restrict__ tb,
                  const float* __restrict__ w2,
                  float* __restrict__ out, float* __restrict__ ostats,
                  int C, int Ct)
{
    __shared__ float tsc[102], tsh[102], w2s[918];
    const float invN = 1.f / 576.f;
    for (int j = threadIdx.x; j < Ct; j += 256){
        float mean = tstats[j] * invN;
        float var  = tstats[Ct + j] * invN - mean * mean;
        float s = tg[j] * rsqrtf(var + EPS);
        tsc[j] = s; tsh[j] = tb[j] - mean * s;
    }
    for (int i = threadIdx.x; i < 9 * Ct; i += 256) w2s[i] = w2[i];
    __syncthreads();
    int item = blockIdx.x * 256 + threadIdx.x;
    if (item >= C * 576) return;
    int c = item / 576, pos = item - c * 576;
    int b = pos / 9, hw = pos - b * 9;
    int h = hw / 3, w = hw - h * 3;

    const float* tp = t_raw + (size_t)b * Ct * 9 + hw;
    float wk[9];
    #pragma unroll
    for (int kk = 0; kk < 9; ++kk) wk[kk] = 0.f;
    for (int j = 0; j < Ct; ++j){
        float t = tp[j * 9] * tsc[j] + tsh[j];
        t = t > 0.f ? t : 0.f;
        #pragma unroll
        for (int kk = 0; kk < 9; ++kk) wk[kk] += t * w2s[kk * Ct + j];
    }
    const float* pb = pin + (size_t)b * C * 9 + c * 9;
    float acc = 0.f;
    #pragma unroll
    for (int ki = 0; ki < 3; ++ki){
        int hh = h + ki - 1;
        bool hok = (unsigned)hh < 3u;
        #pragma unroll
        for (int kj = 0; kj < 3; ++kj){
            int ww = w + kj - 1;
            bool ok = hok && ((unsigned)ww < 3u);
            float v = ok ? pb[hh * 3 + ww] : 0.f;
            acc += wk[ki * 3 + kj] * v;
        }
    }
    out[(size_t)b * C * 9 + c * 9 + hw] = acc;
    float s1 = acc, s2 = acc * acc;
    wave_red2(s1, s2);
    if ((threadIdx.x & 63) == 0){
        atomicAdd(&ostats[c], s1);
        atomicAdd(&ostats[C + c], s2);
    }
}

// ---------------------------------------------------------------------------
// Fused BN+ReLU(+residual) -> conv1x1
// ---------------------------------------------------------------------------
__global__ __launch_bounds__(256)
void bnconv(const float* __restrict__ in, const float* __restrict__ stats,
            const float* __restrict__ g, const float* __restrict__ bta,
            const float* __restrict__ idn, const float* __restrict__ w,
            float* __restrict__ out, int Cin, int Cout)
{
    __shared__ float sc[204], sh[204];
    for (int j = threadIdx.x; j < Cin; j += 256){
        const float invN = 1.f / 576.f;
        float mean = stats[j] * invN;
        float var = stats[Cin + j] * invN - mean * mean;
        float s = g[j] * rsqrtf(var + EPS);
        sc[j] = s; sh[j] = bta[j] - mean * s;
    }
    __syncthreads();
    int item = blockIdx.x * 256 + threadIdx.x;
    if (item >= Cout * 576) return;
    int j = item / 576, pos = item - j * 576;
    int b = pos / 9, hw = pos - b * 9;
    const float* ip = in + (size_t)b * Cin * 9 + hw;
    const float* ir = idn ? idn + (size_t)b * Cin * 9 + hw : nullptr;
    const float* wr = w + (size_t)j * Cin;
    float acc = 0.f;
    #pragma unroll 4
    for (int c = 0; c < Cin; ++c){
        float v = ip[c * 9] * sc[c] + sh[c];
        v = v > 0.f ? v : 0.f;
        if (ir) v += ir[c * 9];
        acc += v * wr[c];
    }
    out[(size_t)b * Cout * 9 + j * 9 + hw] = acc;
}

// ---------------------------------------------------------------------------
// GlobalCovPooling: one workgroup per batch element, all in LDS. Faithful to
// the reference incl. ELEMENTWISE Y-update in Newton-Schulz.
// ---------------------------------------------------------------------------
template<int C, int N, int TB>
__global__ __launch_bounds__(TB)
void covpool(const float* __restrict__ in, float* __restrict__ feat)
{
    __shared__ float X[N * C];
    __shared__ float Ybuf[C * C], Mbuf[C * C], Zbuf[C * C], Z2buf[C * C];
    __shared__ float mu[C];
    __shared__ float scal[2];
    int b = blockIdx.x, tid = threadIdx.x;
    const float* ib = in + (size_t)b * C * N;
    for (int i = tid; i < N * C; i += TB){
        int n = i / C, c = i - n * C;
        X[i] = ib[(size_t)c * N + n];
    }
    __syncthreads();
    if (tid < C){
        float s = 0.f;
        #pragma unroll 5
        for (int n = 0; n < N; ++n) s += X[n * C + tid];
        mu[tid] = s / (float)N;
    }
    __syncthreads();
    constexpr int CC = C * C;
    for (int i = tid; i < CC; i += TB){
        int c = i / C, d = i - c * C;
        float s = 0.f;
        #pragma unroll 5
        for (int n = 0; n < N; ++n) s += X[n * C + c] * X[n * C + d];
        Ybuf[i] = s / (float)N - mu[c] * mu[d];
    }
    __syncthreads();
    if (tid == 0){
        float tr = 0.f;
        for (int c = 0; c < C; ++c) tr += Ybuf[c * C + c];
        scal[0] = 1.f / tr;
    }
    __syncthreads();
    for (int i = tid; i < CC; i += TB){
        int c = i / C, d = i - c * C;
        Ybuf[i] *= scal[0];
        Zbuf[i] = (c == d) ? 1.f : 0.f;
    }
    __syncthreads();
    float* zs = Zbuf; float* zd = Z2buf;
    for (int it = 0; it < 6; ++it){
        for (int i = tid; i < CC; i += TB){
            int c = i / C, d = i - c * C;
            float s = 0.f;
            #pragma unroll 6
            for (int e = 0; e < C; ++e) s += zs[c * C + e] * Ybuf[e * C + d];
            Mbuf[i] = ((c == d) ? 3.f : 0.f) - s;
        }
        __syncthreads();
        for (int i = tid; i < CC; i += TB){
            int c = i / C, d = i - c * C;
            float s = 0.f;
            #pragma unroll 6
            for (int e = 0; e < C; ++e) s += Mbuf[c * C + e] * zs[e * C + d];
            zd[i] = 0.5f * s;
        }
        for (int i = tid; i < CC; i += TB) Ybuf[i] *= 0.5f * Mbuf[i];   // elementwise, as in source
        __syncthreads();
        float* t = zs; zs = zd; zd = t;
    }
    if (tid == 0){
        float tr = 0.f;
        for (int c = 0; c < C; ++c) tr += Ybuf[c * C + c];
        scal[1] = sqrtf(tr);
    }
    __syncthreads();
    if (tid < C){
        float s = 0.f;
        #pragma unroll 6
        for (int c = 0; c < C; ++c) s += Ybuf[c * C + tid];
        feat[(size_t)b * C + tid] = scal[1] * s / (float)C;
    }
}

// ---------------------------------------------------------------------------
// Head: concat feats, BN over batch, ReLU, linear, softmax. Single workgroup.
// ---------------------------------------------------------------------------
__global__ __launch_bounds__(256)
void head_k(const float* __restrict__ feat1, const float* __restrict__ feat2,
            const float* __restrict__ hg, const float* __restrict__ hb,
            const float* __restrict__ lw, const float* __restrict__ lb,
            float* __restrict__ out)
{
    __shared__ float f[46 * 64];
    int tid = threadIdx.x;
    for (int i = tid; i < 46 * 64; i += 256){
        int ch = i / 64, b = i - ch * 64;
        f[i] = ch < 30 ? feat1[b * 30 + ch] : feat2[b * 16 + (ch - 30)];
    }
    __syncthreads();
    if (tid < 46){
        float s = 0.f, s2 = 0.f;
        for (int b = 0; b < 64; ++b){ float v = f[tid * 64 + b]; s += v; s2 += v * v; }
        float mean = s / 64.f, var = s2 / 64.f - mean * mean;
        float sc = hg[tid] * rsqrtf(var + EPS), sh = hb[tid] - mean * sc;
        for (int b = 0; b < 64; ++b){
            float v = f[tid * 64 + b] * sc + sh;
            f[tid * 64 + b] = v > 0.f ? v : 0.f;
        }
    }
    __syncthreads();
    if (tid < 64){
        int b = tid;
        float l[16];
        float m = -1e30f;
        for (int o = 0; o < 16; ++o){
            float a = lb[o];
            for (int ch = 0; ch < 46; ++ch) a += f[ch * 64 + b] * lw[o * 46 + ch];
            l[o] = a; m = fmaxf(m, a);
        }
        float se = 0.f;
        for (int o = 0; o < 16; ++o){ l[o] = expf(l[o] - m); se += l[o]; }
        float inv = 1.f / se;
        for (int o = 0; o < 16; ++o) out[b * 16 + o] = l[o] * inv;
    }
}

extern "C" void kernel_launch(void* const* d_in, const int* in_sizes, int n_in,
                              void* d_out, int out_size, void* d_ws, size_t ws_size,
                              hipStream_t stream)
{
    (void)in_sizes; (void)n_in; (void)out_size; (void)ws_size;
    const float* x        = (const float*)d_in[0];
    const float* y        = (const float*)d_in[1];
    const float* blk_w1   = (const float*)d_in[2];
    const float* blk_ig   = (const float*)d_in[3];
    const float* blk_ib   = (const float*)d_in[4];
    const float* blk_w2_5 = (const float*)d_in[5];
    const float* blk_w2_7 = (const float*)d_in[6];
    const float* blk_w2_9 = (const float*)d_in[7];
    const float* blk_g    = (const float*)d_in[8];
    const float* blk_b    = (const float*)d_in[9];
    const float* blk_conv = (const float*)d_in[10];
    const float* loc_w1 = (const float*)d_in[11];
    const float* loc_g  = (const float*)d_in[12];
    const float* loc_b  = (const float*)d_in[13];
    const float* loc_w2 = (const float*)d_in[14];
    const float* glb_w1 = (const float*)d_in[15];
    const float* glb_g  = (const float*)d_in[16];
    const float* glb_b  = (const float*)d_in[17];
    const float* glb_w2 = (const float*)d_in[18];
    const float* c3_w1 = (const float*)d_in[19];
    const float* c3_g  = (const float*)d_in[20];
    const float* c3_b  = (const float*)d_in[21];
    const float* c3_w2 = (const float*)d_in[22];
    const float* c4_w1 = (const float*)d_in[23];
    const float* c4_g  = (const float*)d_in[24];
    const float* c4_b  = (const float*)d_in[25];
    const float* c4_w2 = (const float*)d_in[26];
    const float* c5_w1 = (const float*)d_in[27];
    const float* c5_g  = (const float*)d_in[28];
    const float* c5_b  = (const float*)d_in[29];
    const float* c5_w2 = (const float*)d_in[30];
    const float* p1 = (const float*)d_in[31];
    const float* p2 = (const float*)d_in[32];
    const float* p3 = (const float*)d_in[33];
    const float* bn1g = (const float*)d_in[34];
    const float* bn1b = (const float*)d_in[35];
    const float* bn2g = (const float*)d_in[36];
    const float* bn2b = (const float*)d_in[37];
    const float* bn3g = (const float*)d_in[38];
    const float* bn3b = (const float*)d_in[39];
    const float* hg = (const float*)d_in[40];
    const float* hb = (const float*)d_in[41];
    const float* lw = (const float*)d_in[42];
    const float* lb = (const float*)d_in[43];

    float* ws = (float*)d_ws;
    size_t off = 0;
    auto alloc = [&](size_t n){ float* p = ws + off; off += n; return p; };
    float* bufA    = alloc(432000);
    float* bufB    = alloc(432000);
    float* scratch = alloc(1944000);   // branch1 t_raw(3)+o_raw(3); branch2 aliases this
    float* feat1   = alloc(64 * 30);
    float* feat2   = alloc(64 * 16);
    float* stats   = alloc(2288);

    float* t_raw = scratch;            // 3 x 216000
    float* o_raw = scratch + 648000;   // 3 x 432000

    hipMemsetAsync(stats, 0, 2288 * sizeof(float), stream);

    // ---- branch 1: 3 IVoubottleneck blocks ----
    const float* cur = x;
    float* dst = bufA;
    for (int bi = 0; bi < 3; ++bi){
        float* st_t = stats + bi * 90;          // 3 x (15 sum + 15 sumsq)
        float* st_o = stats + 270 + bi * 180;   // 3 x (30 sum + 30 sumsq)
        conv1x1_k<<<dim3(844, 1, 3), 256, 0, stream>>>(
            cur, blk_w1 + bi * 1350, t_raw, st_t, 30, 15, 225, 64, 450, 216000, 30);
        invol_b1_all<<<dim3(64, 4, 3), 256, 0, stream>>>(
            cur, t_raw, st_t, blk_ig + bi * 45, blk_ib + bi * 45,
            blk_w2_5 + bi * 750, blk_w2_7 + bi * 1470, blk_w2_9 + bi * 2430,
            o_raw, st_o);
        blockend<<<1688, 256, 0, stream>>>(o_raw, o_raw + 432000, o_raw + 864000,
                                           st_o, st_o + 60, st_o + 120,
                                           blk_g + bi * 90, blk_b + bi * 90, blk_conv + bi * 2700,
                                           cur, dst);
        cur = dst;
        dst = (bi == 0) ? bufB : bufA;
    }
    covpool<30, 225, 1024><<<64, 1024, 0, stream>>>(cur, feat1);

    // ---- branch 2: cross attention (aliases scratch; branch-1 uses are done) ----
    float* t_loc = scratch;
    float* t_glb = t_loc + 58752;
    float* o_idn = t_glb + 58752;
    float* t3    = o_idn + 117504;
    float* o3    = t3 + 58752;
    float* o5    = o3 + 117504;
    float* t4    = o5 + 58752;
    float* o6    = t4 + 29376;
    float* o8    = o6 + 58752;
    float* t5    = o8 + 29376;
    float* o9    = t5 + 14400;
    float* o11   = o9 + 29376;

    float* s_tloc = stats + 810;
    float* s_tglb = s_tloc + 204;
    float* s_t3   = s_tglb + 204;
    float* s_o3   = s_t3 + 204;
    float* s_t4   = s_o3 + 408;
    float* s_o6   = s_t4 + 102;
    float* s_t5   = s_o6 + 204;
    float* s_o9   = s_t5 + 50;

    conv_dual<<<dim3(230, 1, 2), 256, 0, stream>>>(y, loc_w1, glb_w1, t_loc, t_glb,
                                                   s_tloc, s_tglb, 204, 102);
    crossatt_fused<<<459, 256, 0, stream>>>(y, t_loc, t_glb, s_tloc, s_tglb,
                                            loc_g, loc_b, glb_g, glb_b,
                                            loc_w2, glb_w2, o_idn);
    // c3
    conv1x1_k<<<230, 256, 0, stream>>>(o_idn, c3_w1, t3, s_t3, 204, 102, 9, 64, 0, 0, 0);
    invol3_fused<<<459, 256, 0, stream>>>(o_idn, t3, s_t3, c3_g, c3_b, c3_w2, o3, s_o3, 204, 102);
    bnconv<<<230, 256, 0, stream>>>(o3, s_o3, bn1g, bn1b, o_idn, p1, o5, 204, 102);
    // c4
    conv1x1_k<<<115, 256, 0, stream>>>(o5, c4_w1, t4, s_t4, 102, 51, 9, 64, 0, 0, 0);
    invol3_fused<<<230, 256, 0, stream>>>(o5, t4, s_t4, c4_g, c4_b, c4_w2, o6, s_o6, 102, 51);
    bnconv<<<115, 256, 0, stream>>>(o6, s_o6, bn2g, bn2b, nullptr, p2, o8, 102, 51);
    // c5
    conv1x1_k<<<57, 256, 0, stream>>>(o8, c5_w1, t5, s_t5, 51, 25, 9, 64, 0, 0, 0);
    invol3_fused<<<115, 256, 0, stream>>>(o8, t5, s_t5, c5_g, c5_b, c5_w2, o9, s_o9, 51, 25);
    bnconv<<<36, 256, 0, stream>>>(o9, s_o9, bn3g, bn3b, o8, p3, o11, 51, 16);
    covpool<16, 9, 256><<<64, 256, 0, stream>>>(o11, feat2);

    // ---- head ----
    head_k<<<1, 256, 0, stream>>>(feat1, feat2, hg, hb, lw, lb, (float*)d_out);
}

// Round 6
// 1233.683 us; speedup vs baseline: 1.7721x; 1.0648x over previous
//
#include <hip/hip_runtime.h>
#include <math.h>

#define EPS 1e-5f

__device__ inline void wave_red2(float& s1, float& s2){
    for (int off = 32; off; off >>= 1){
        s1 += __shfl_down(s1, off, 64);
        s2 += __shfl_down(s2, off, 64);
    }
}

// ---------------------------------------------------------------------------
// Generic conv1x1 (out[b,j,hw] = sum_c in[b,c,hw]*w[j,c]) with optional
// per-channel (sum, sumsq) stats accumulation. npos % 64 == 0 so j is
// wave-uniform -> weight reads go through the scalar pipe (readfirstlane).
// ---------------------------------------------------------------------------
__global__ __launch_bounds__(256)
void conv1x1_k(const float* __restrict__ in, const float* __restrict__ w,
               float* __restrict__ out, float* __restrict__ stats,
               int Cin, int Cout, int HW, int B,
               int wStrideZ, int outStrideZ, int statsStrideZ)
{
    const float* wz = w + (size_t)blockIdx.z * wStrideZ;
    float* oz = out + (size_t)blockIdx.z * outStrideZ;
    float* sz = stats ? stats + (size_t)blockIdx.z * statsStrideZ : nullptr;
    int npos = B * HW;
    int total = Cout * npos;
    int item = blockIdx.x * blockDim.x + threadIdx.x;
    if (item >= total) return;
    int j = item / npos;
    int pos = item - j * npos;
    int b = pos / HW, hw = pos - b * HW;
    int ju = __builtin_amdgcn_readfirstlane(j);
    const float* ip = in + (size_t)b * Cin * HW + hw;
    const float* wr = wz + (size_t)ju * Cin;
    float acc = 0.f;
    #pragma unroll 4
    for (int c = 0; c < Cin; ++c) acc += ip[(size_t)c * HW] * wr[c];
    oz[(size_t)b * Cout * HW + (size_t)j * HW + hw] = acc;
    if (sz){
        float s1 = acc, s2 = acc * acc;
        wave_red2(s1, s2);
        if ((threadIdx.x & 63) == 0){
            atomicAdd(&sz[ju], s1);
            atomicAdd(&sz[Cout + ju], s2);
        }
    }
}

// ---------------------------------------------------------------------------
// Dual conv1x1 for branch-2 (t_loc & t_glb in one launch). HW=9, B=64.
// ---------------------------------------------------------------------------
__global__ __launch_bounds__(256)
void conv_dual(const float* __restrict__ in,
               const float* __restrict__ wA, const float* __restrict__ wB,
               float* __restrict__ outA, float* __restrict__ outB,
               float* __restrict__ stA, float* __restrict__ stB,
               int Cin, int Cout)
{
    const float* w = blockIdx.z ? wB : wA;
    float* out = blockIdx.z ? outB : outA;
    float* st  = blockIdx.z ? stB : stA;
    int total = Cout * 576;
    int item = blockIdx.x * 256 + threadIdx.x;
    if (item >= total) return;
    int j = item / 576, pos = item - j * 576;
    int b = pos / 9, hw = pos - b * 9;
    int ju = __builtin_amdgcn_readfirstlane(j);
    const float* ip = in + (size_t)b * Cin * 9 + hw;
    const float* wr = w + (size_t)ju * Cin;
    float acc = 0.f;
    #pragma unroll 4
    for (int c = 0; c < Cin; ++c) acc += ip[c * 9] * wr[c];
    out[(size_t)b * Cout * 9 + j * 9 + hw] = acc;
    float s1 = acc, s2 = acc * acc;
    wave_red2(s1, s2);
    if ((threadIdx.x & 63) == 0){
        atomicAdd(&st[ju], s1);
        atomicAdd(&st[Cout + ju], s2);
    }
}

// ---------------------------------------------------------------------------
// FUSED branch-1 involution: block = (b, g, channel-half, ksize).
// w2 is read DIRECTLY from global with block-uniform addresses -> s_load
// (scalar pipe), so the inner loop only uses LDS for the 8 input channels.
// ---------------------------------------------------------------------------
template<int K>
__device__ void invol_b1_dev(const float* __restrict__ in, const float* __restrict__ t_raw,
                             const float* __restrict__ tstats,
                             const float* __restrict__ tg, const float* __restrict__ tb,
                             const float* __restrict__ w2,
                             float* __restrict__ o_raw, float* __restrict__ ostats,
                             float* lds, int b, int g, int c0, int nch)
{
    constexpr int KK = K * K, P = (K - 1) / 2;
    float* in_s = lds;            // 8*225
    float* scb  = lds + 1800;     // 15
    float* shb  = lds + 1815;     // 15
    int tid = threadIdx.x;

    if (tid < 15){
        const float invN = 1.f / 14400.f;
        float mean = tstats[tid] * invN;
        float var  = tstats[15 + tid] * invN - mean * mean;
        float s = tg[tid] * rsqrtf(var + EPS);
        scb[tid] = s; shb[tid] = tb[tid] - mean * s;
    }
    const float* w2g = w2 + (size_t)g * KK * 15;   // block-uniform base
    const float* inb = in + (size_t)b * 6750 + (size_t)(g * 15 + c0) * 225;
    int stage = nch * 225;
    for (int i = tid; i < stage; i += 256) in_s[i] = inb[i];
    __syncthreads();

    bool act = tid < 225;
    int p = act ? tid : 224;
    int h = p / 15, w = p - h * 15;

    float treg[15];
    const float* trb = t_raw + (size_t)b * 3375 + p;
    #pragma unroll
    for (int j = 0; j < 15; ++j){
        float v = trb[j * 225] * scb[j] + shb[j];
        treg[j] = v > 0.f ? v : 0.f;
    }

    float acc[8];
    #pragma unroll
    for (int cc = 0; cc < 8; ++cc) acc[cc] = 0.f;

    for (int ki = 0; ki < K; ++ki){
        int hh = h + ki - P;
        bool hok = (unsigned)hh < 15u;
        const float* w2row = w2g + ki * K * 15;    // uniform (loop var)
        #pragma unroll
        for (int kj = 0; kj < K; ++kj){
            int ww = w + kj - P;
            bool ok = hok && ((unsigned)ww < 15u);
            float wkv = 0.f;
            #pragma unroll
            for (int j = 0; j < 15; ++j) wkv += treg[j] * w2row[kj * 15 + j];
            float sc2 = ok ? wkv : 0.f;
            int offr = ok ? hh * 15 + ww : 0;
            #pragma unroll
            for (int cc = 0; cc < 8; ++cc) acc[cc] += sc2 * in_s[cc * 225 + offr];
        }
    }

    float* ob = o_raw + (size_t)b * 6750 + (size_t)(g * 15 + c0) * 225;
    for (int cc = 0; cc < nch; ++cc){
        float val = act ? acc[cc] : 0.f;
        if (act) ob[cc * 225 + p] = val;
        float s1 = val, s2 = val * val;
        wave_red2(s1, s2);
        if ((tid & 63) == 0){
            atomicAdd(&ostats[g * 15 + c0 + cc], s1);
            atomicAdd(&ostats[30 + g * 15 + c0 + cc], s2);
        }
    }
}

__global__ __launch_bounds__(256)
void invol_b1_all(const float* __restrict__ in, const float* __restrict__ t_raw3,
                  const float* __restrict__ tstats3,
                  const float* __restrict__ tg3, const float* __restrict__ tb3,
                  const float* __restrict__ w2_5, const float* __restrict__ w2_7,
                  const float* __restrict__ w2_9,
                  float* __restrict__ o_raw3, float* __restrict__ ostats3)
{
    __shared__ float lds[1830];
    int b = blockIdx.x;
    int g = blockIdx.y >> 1;
    int c0 = (blockIdx.y & 1) * 8;
    int nch = c0 ? 7 : 8;
    int ii = blockIdx.z;
    if (ii == 0)
        invol_b1_dev<5>(in, t_raw3,          tstats3,      tg3,      tb3,      w2_5, o_raw3,          ostats3,       lds, b, g, c0, nch);
    else if (ii == 1)
        invol_b1_dev<7>(in, t_raw3 + 216000, tstats3 + 30, tg3 + 15, tb3 + 15, w2_7, o_raw3 + 432000, ostats3 + 60,  lds, b, g, c0, nch);
    else
        invol_b1_dev<9>(in, t_raw3 + 432000, tstats3 + 60, tg3 + 30, tb3 + 30, w2_9, o_raw3 + 864000, ostats3 + 120, lds, b, g, c0, nch);
}

// ---------------------------------------------------------------------------
// Branch-1 block end: out_new = conv1x1(concat(relu(bn(o_ii))), conv) + out_old
// ---------------------------------------------------------------------------
__global__ __launch_bounds__(256)
void blockend(const float* __restrict__ o0, const float* __restrict__ o1,
              const float* __restrict__ o2,
              const float* __restrict__ s0, const float* __restrict__ s1,
              const float* __restrict__ s2,
              const float* __restrict__ g, const float* __restrict__ bb,
              const float* __restrict__ conv,
              const float* __restrict__ oldout, float* __restrict__ newout)
{
    __shared__ float sc[90], sh[90];
    int tid = threadIdx.x;
    if (tid < 90){
        int ii = tid / 30, cc = tid - ii * 30;
        const float* st = ii == 0 ? s0 : (ii == 1 ? s1 : s2);
        const float invN = 1.f / 14400.f;
        float mean = st[cc] * invN;
        float var = st[30 + cc] * invN - mean * mean;
        float s = g[tid] * rsqrtf(var + EPS);
        sc[tid] = s; sh[tid] = bb[tid] - mean * s;
    }
    __syncthreads();
    int item = blockIdx.x * 256 + tid;
    if (item >= 432000) return;
    int c = item / 14400, pos = item - c * 14400;
    int b = pos / 225, hw = pos - b * 225;
    int cu = __builtin_amdgcn_readfirstlane(c);
    float acc = oldout[(size_t)b * 6750 + c * 225 + hw];
    const float* cr = conv + cu * 90;              // scalar loads
    const float* bases[3] = {o0, o1, o2};
    #pragma unroll
    for (int ii = 0; ii < 3; ++ii){
        const float* op = bases[ii] + (size_t)b * 6750 + hw;
        #pragma unroll 6
        for (int cc = 0; cc < 30; ++cc){
            float v = op[cc * 225] * sc[ii * 30 + cc] + sh[ii * 30 + cc];
            v = v > 0.f ? v : 0.f;
            acc += v * cr[ii * 30 + cc];
        }
    }
    newout[(size_t)b * 6750 + c * 225 + hw] = acc;
}

// ---------------------------------------------------------------------------
// Fused cross-attention front: o = y * (loc(y) + glb(y)). loc_w2 row base is
// forced wave-uniform via readfirstlane -> scalar loads; glb_w2 is
// block-uniform -> scalar automatically.
// ---------------------------------------------------------------------------
__global__ __launch_bounds__(256)
void crossatt_fused(const float* __restrict__ y,
                    const float* __restrict__ t_loc, const float* __restrict__ t_glb,
                    const float* __restrict__ s_tloc, const float* __restrict__ s_tglb,
                    const float* __restrict__ lg, const float* __restrict__ lb,
                    const float* __restrict__ gg, const float* __restrict__ gb,
                    const float* __restrict__ loc_w2, const float* __restrict__ glb_w2,
                    float* __restrict__ out)
{
    __shared__ float lsc[102], lsh[102], gsc[102], gsh[102];
    const float invN = 1.f / 576.f;
    for (int j = threadIdx.x; j < 102; j += 256){
        float m1 = s_tloc[j] * invN;
        float v1 = s_tloc[102 + j] * invN - m1 * m1;
        float a1 = lg[j] * rsqrtf(v1 + EPS);
        lsc[j] = a1; lsh[j] = lb[j] - m1 * a1;
        float m2 = s_tglb[j] * invN;
        float v2 = s_tglb[102 + j] * invN - m2 * m2;
        float a2 = gg[j] * rsqrtf(v2 + EPS);
        gsc[j] = a2; gsh[j] = gb[j] - m2 * a2;
    }
    __syncthreads();
    int item = blockIdx.x * 256 + threadIdx.x;
    if (item >= 204 * 576) return;
    int c = item / 576, pos = item - c * 576;
    int b = pos / 9, hw = pos - b * 9;
    int h = hw / 3, w = hw - h * 3;
    int cu = __builtin_amdgcn_readfirstlane(c);

    const float* tl = t_loc + (size_t)b * 918 + hw;
    const float* tg_ = t_glb + (size_t)b * 918 + hw;
    const float* wl = loc_w2 + (size_t)cu * 918;   // wave-uniform -> s_load
    float wk[9];
    #pragma unroll
    for (int kk = 0; kk < 9; ++kk) wk[kk] = 0.f;
    for (int j = 0; j < 102; ++j){
        float a = tl[j * 9] * lsc[j] + lsh[j];
        a = a > 0.f ? a : 0.f;
        float g2 = tg_[j * 9] * gsc[j] + gsh[j];
        g2 = g2 > 0.f ? g2 : 0.f;
        #pragma unroll
        for (int kk = 0; kk < 9; ++kk)
            wk[kk] += a * wl[kk * 102 + j] + g2 * glb_w2[kk * 102 + j];
    }
    const float* pb = y + (size_t)b * 1836 + c * 9;
    float acc = 0.f;
    #pragma unroll
    for (int ki = 0; ki < 3; ++ki){
        int hh = h + ki - 1;
        bool hok = (unsigned)hh < 3u;
        #pragma unroll
        for (int kj = 0; kj < 3; ++kj){
            int ww = w + kj - 1;
            bool ok = hok && ((unsigned)ww < 3u);
            float v = ok ? pb[hh * 3 + ww] : 0.f;
            acc += wk[ki * 3 + kj] * v;
        }
    }
    out[(size_t)b * 1836 + c * 9 + hw] = pb[hw] * acc;
}

// ---------------------------------------------------------------------------
// Fused groups==1 involution (wkgen + apply + stats) for c3/c4/c5.
// w2 block-uniform -> scalar loads; no LDS staging of w2.
// ---------------------------------------------------------------------------
__global__ __launch_bounds__(256)
void invol3_fused(const float* __restrict__ pin, const float* __restrict__ t_raw,
                  const float* __restrict__ tstats,
                  const float* __restrict__ tg, const float* __restrict__ tb,
                  const float* __restrict__ w2,
                  float* __restrict__ out, float* __restrict__ ostats,
                  int C, int Ct)
{
    __shared__ float tsc[102], tsh[102];
    const float invN = 1.f / 576.f;
    for (int j = threadIdx.x; j < Ct; j += 256){
        float mean = tstats[j] * invN;
        float var  = tstats[Ct + j] * invN - mean * mean;
        float s = tg[j] * rsqrtf(var + EPS);
        tsc[j] = s; tsh[j] = tb[j] - mean * s;
    }
    __syncthreads();
    int item = blockIdx.x * 256 + threadIdx.x;
    if (item >= C * 576) return;
    int c = item / 576, pos = item - c * 576;
    int b = pos / 9, hw = pos - b * 9;
    int h = hw / 3, w = hw - h * 3;

    const float* tp = t_raw + (size_t)b * Ct * 9 + hw;
    float wk[9];
    #pragma unroll
    for (int kk = 0; kk < 9; ++kk) wk[kk] = 0.f;
    for (int j = 0; j < Ct; ++j){
        float t = tp[j * 9] * tsc[j] + tsh[j];
        t = t > 0.f ? t : 0.f;
        #pragma unroll
        for (int kk = 0; kk < 9; ++kk) wk[kk] += t * w2[kk * Ct + j];
    }
    const float* pb = pin + (size_t)b * C * 9 + c * 9;
    float acc = 0.f;
    #pragma unroll
    for (int ki = 0; ki < 3; ++ki){
        int hh = h + ki - 1;
        bool hok = (unsigned)hh < 3u;
        #pragma unroll
        for (int kj = 0; kj < 3; ++kj){
            int ww = w + kj - 1;
            bool ok = hok && ((unsigned)ww < 3u);
            float v = ok ? pb[hh * 3 + ww] : 0.f;
            acc += wk[ki * 3 + kj] * v;
        }
    }
    out[(size_t)b * C * 9 + c * 9 + hw] = acc;
    float s1 = acc, s2 = acc * acc;
    wave_red2(s1, s2);
    if ((threadIdx.x & 63) == 0){
        int cu = __builtin_amdgcn_readfirstlane(c);
        atomicAdd(&ostats[cu], s1);
        atomicAdd(&ostats[C + cu], s2);
    }
}

// ---------------------------------------------------------------------------
// Fused BN+ReLU(+residual) -> conv1x1
// ---------------------------------------------------------------------------
__global__ __launch_bounds__(256)
void bnconv(const float* __restrict__ in, const float* __restrict__ stats,
            const float* __restrict__ g, const float* __restrict__ bta,
            const float* __restrict__ idn, const float* __restrict__ w,
            float* __restrict__ out, int Cin, int Cout)
{
    __shared__ float sc[204], sh[204];
    for (int j = threadIdx.x; j < Cin; j += 256){
        const float invN = 1.f / 576.f;
        float mean = stats[j] * invN;
        float var = stats[Cin + j] * invN - mean * mean;
        float s = g[j] * rsqrtf(var + EPS);
        sc[j] = s; sh[j] = bta[j] - mean * s;
    }
    __syncthreads();
    int item = blockIdx.x * 256 + threadIdx.x;
    if (item >= Cout * 576) return;
    int j = item / 576, pos = item - j * 576;
    int b = pos / 9, hw = pos - b * 9;
    int ju = __builtin_amdgcn_readfirstlane(j);
    const float* ip = in + (size_t)b * Cin * 9 + hw;
    const float* ir = idn ? idn + (size_t)b * Cin * 9 + hw : nullptr;
    const float* wr = w + (size_t)ju * Cin;
    float acc = 0.f;
    #pragma unroll 4
    for (int c = 0; c < Cin; ++c){
        float v = ip[c * 9] * sc[c] + sh[c];
        v = v > 0.f ? v : 0.f;
        if (ir) v += ir[c * 9];
        acc += v * wr[c];
    }
    out[(size_t)b * Cout * 9 + j * 9 + hw] = acc;
}

// ---------------------------------------------------------------------------
// GlobalCovPooling: one workgroup per batch element, all in LDS. Faithful to
// the reference incl. ELEMENTWISE Y-update in Newton-Schulz.
// ---------------------------------------------------------------------------
template<int C, int N, int TB>
__global__ __launch_bounds__(TB)
void covpool(const float* __restrict__ in, float* __restrict__ feat)
{
    __shared__ float X[N * C];
    __shared__ float Ybuf[C * C], Mbuf[C * C], Zbuf[C * C], Z2buf[C * C];
    __shared__ float mu[C];
    __shared__ float scal[2];
    int b = blockIdx.x, tid = threadIdx.x;
    const float* ib = in + (size_t)b * C * N;
    for (int i = tid; i < N * C; i += TB){
        int n = i / C, c = i - n * C;
        X[i] = ib[(size_t)c * N + n];
    }
    __syncthreads();
    if (tid < C){
        float s = 0.f;
        #pragma unroll 5
        for (int n = 0; n < N; ++n) s += X[n * C + tid];
        mu[tid] = s / (float)N;
    }
    __syncthreads();
    constexpr int CC = C * C;
    for (int i = tid; i < CC; i += TB){
        int c = i / C, d = i - c * C;
        float s = 0.f;
        #pragma unroll 5
        for (int n = 0; n < N; ++n) s += X[n * C + c] * X[n * C + d];
        Ybuf[i] = s / (float)N - mu[c] * mu[d];
    }
    __syncthreads();
    if (tid == 0){
        float tr = 0.f;
        for (int c = 0; c < C; ++c) tr += Ybuf[c * C + c];
        scal[0] = 1.f / tr;
    }
    __syncthreads();
    for (int i = tid; i < CC; i += TB){
        int c = i / C, d = i - c * C;
        Ybuf[i] *= scal[0];
        Zbuf[i] = (c == d) ? 1.f : 0.f;
    }
    __syncthreads();
    float* zs = Zbuf; float* zd = Z2buf;
    for (int it = 0; it < 6; ++it){
        for (int i = tid; i < CC; i += TB){
            int c = i / C, d = i - c * C;
            float s = 0.f;
            #pragma unroll 6
            for (int e = 0; e < C; ++e) s += zs[c * C + e] * Ybuf[e * C + d];
            Mbuf[i] = ((c == d) ? 3.f : 0.f) - s;
        }
        __syncthreads();
        for (int i = tid; i < CC; i += TB){
            int c = i / C, d = i - c * C;
            float s = 0.f;
            #pragma unroll 6
            for (int e = 0; e < C; ++e) s += Mbuf[c * C + e] * zs[e * C + d];
            zd[i] = 0.5f * s;
        }
        for (int i = tid; i < CC; i += TB) Ybuf[i] *= 0.5f * Mbuf[i];   // elementwise, as in source
        __syncthreads();
        float* t = zs; zs = zd; zd = t;
    }
    if (tid == 0){
        float tr = 0.f;
        for (int c = 0; c < C; ++c) tr += Ybuf[c * C + c];
        scal[1] = sqrtf(tr);
    }
    __syncthreads();
    if (tid < C){
        float s = 0.f;
        #pragma unroll 6
        for (int c = 0; c < C; ++c) s += Ybuf[c * C + tid];
        feat[(size_t)b * C + tid] = scal[1] * s / (float)C;
    }
}

// ---------------------------------------------------------------------------
// Head: concat feats, BN over batch, ReLU, linear, softmax. Single workgroup.
// ---------------------------------------------------------------------------
__global__ __launch_bounds__(256)
void head_k(const float* __restrict__ feat1, const float* __restrict__ feat2,
            const float* __restrict__ hg, const float* __restrict__ hb,
            const float* __restrict__ lw, const float* __restrict__ lb,
            float* __restrict__ out)
{
    __shared__ float f[46 * 64];
    int tid = threadIdx.x;
    for (int i = tid; i < 46 * 64; i += 256){
        int ch = i / 64, b = i - ch * 64;
        f[i] = ch < 30 ? feat1[b * 30 + ch] : feat2[b * 16 + (ch - 30)];
    }
    __syncthreads();
    if (tid < 46){
        float s = 0.f, s2 = 0.f;
        for (int b = 0; b < 64; ++b){ float v = f[tid * 64 + b]; s += v; s2 += v * v; }
        float mean = s / 64.f, var = s2 / 64.f - mean * mean;
        float sc = hg[tid] * rsqrtf(var + EPS), sh = hb[tid] - mean * sc;
        for (int b = 0; b < 64; ++b){
            float v = f[tid * 64 + b] * sc + sh;
            f[tid * 64 + b] = v > 0.f ? v : 0.f;
        }
    }
    __syncthreads();
    if (tid < 64){
        int b = tid;
        float l[16];
        float m = -1e30f;
        for (int o = 0; o < 16; ++o){
            float a = lb[o];
            for (int ch = 0; ch < 46; ++ch) a += f[ch * 64 + b] * lw[o * 46 + ch];
            l[o] = a; m = fmaxf(m, a);
        }
        float se = 0.f;
        for (int o = 0; o < 16; ++o){ l[o] = expf(l[o] - m); se += l[o]; }
        float inv = 1.f / se;
        for (int o = 0; o < 16; ++o) out[b * 16 + o] = l[o] * inv;
    }
}

extern "C" void kernel_launch(void* const* d_in, const int* in_sizes, int n_in,
                              void* d_out, int out_size, void* d_ws, size_t ws_size,
                              hipStream_t stream)
{
    (void)in_sizes; (void)n_in; (void)out_size; (void)ws_size;
    const float* x        = (const float*)d_in[0];
    const float* y        = (const float*)d_in[1];
    const float* blk_w1   = (const float*)d_in[2];
    const float* blk_ig   = (const float*)d_in[3];
    const float* blk_ib   = (const float*)d_in[4];
    const float* blk_w2_5 = (const float*)d_in[5];
    const float* blk_w2_7 = (const float*)d_in[6];
    const float* blk_w2_9 = (const float*)d_in[7];
    const float* blk_g    = (const float*)d_in[8];
    const float* blk_b    = (const float*)d_in[9];
    const float* blk_conv = (const float*)d_in[10];
    const float* loc_w1 = (const float*)d_in[11];
    const float* loc_g  = (const float*)d_in[12];
    const float* loc_b  = (const float*)d_in[13];
    const float* loc_w2 = (const float*)d_in[14];
    const float* glb_w1 = (const float*)d_in[15];
    const float* glb_g  = (const float*)d_in[16];
    const float* glb_b  = (const float*)d_in[17];
    const float* glb_w2 = (const float*)d_in[18];
    const float* c3_w1 = (const float*)d_in[19];
    const float* c3_g  = (const float*)d_in[20];
    const float* c3_b  = (const float*)d_in[21];
    const float* c3_w2 = (const float*)d_in[22];
    const float* c4_w1 = (const float*)d_in[23];
    const float* c4_g  = (const float*)d_in[24];
    const float* c4_b  = (const float*)d_in[25];
    const float* c4_w2 = (const float*)d_in[26];
    const float* c5_w1 = (const float*)d_in[27];
    const float* c5_g  = (const float*)d_in[28];
    const float* c5_b  = (const float*)d_in[29];
    const float* c5_w2 = (const float*)d_in[30];
    const float* p1 = (const float*)d_in[31];
    const float* p2 = (const float*)d_in[32];
    const float* p3 = (const float*)d_in[33];
    const float* bn1g = (const float*)d_in[34];
    const float* bn1b = (const float*)d_in[35];
    const float* bn2g = (const float*)d_in[36];
    const float* bn2b = (const float*)d_in[37];
    const float* bn3g = (const float*)d_in[38];
    const float* bn3b = (const float*)d_in[39];
    const float* hg = (const float*)d_in[40];
    const float* hb = (const float*)d_in[41];
    const float* lw = (const float*)d_in[42];
    const float* lb = (const float*)d_in[43];

    float* ws = (float*)d_ws;
    size_t off = 0;
    auto alloc = [&](size_t n){ float* p = ws + off; off += n; return p; };
    float* bufA    = alloc(432000);
    float* bufB    = alloc(432000);
    float* scratch = alloc(1944000);   // branch1 t_raw(3)+o_raw(3); branch2 aliases this
    float* feat1   = alloc(64 * 30);
    float* feat2   = alloc(64 * 16);
    float* stats   = alloc(2288);

    float* t_raw = scratch;            // 3 x 216000
    float* o_raw = scratch + 648000;   // 3 x 432000

    hipMemsetAsync(stats, 0, 2288 * sizeof(float), stream);

    // ---- branch 1: 3 IVoubottleneck blocks ----
    const float* cur = x;
    float* dst = bufA;
    for (int bi = 0; bi < 3; ++bi){
        float* st_t = stats + bi * 90;          // 3 x (15 sum + 15 sumsq)
        float* st_o = stats + 270 + bi * 180;   // 3 x (30 sum + 30 sumsq)
        conv1x1_k<<<dim3(844, 1, 3), 256, 0, stream>>>(
            cur, blk_w1 + bi * 1350, t_raw, st_t, 30, 15, 225, 64, 450, 216000, 30);
        invol_b1_all<<<dim3(64, 4, 3), 256, 0, stream>>>(
            cur, t_raw, st_t, blk_ig + bi * 45, blk_ib + bi * 45,
            blk_w2_5 + bi * 750, blk_w2_7 + bi * 1470, blk_w2_9 + bi * 2430,
            o_raw, st_o);
        blockend<<<1688, 256, 0, stream>>>(o_raw, o_raw + 432000, o_raw + 864000,
                                           st_o, st_o + 60, st_o + 120,
                                           blk_g + bi * 90, blk_b + bi * 90, blk_conv + bi * 2700,
                                           cur, dst);
        cur = dst;
        dst = (bi == 0) ? bufB : bufA;
    }
    covpool<30, 225, 1024><<<64, 1024, 0, stream>>>(cur, feat1);

    // ---- branch 2: cross attention (aliases scratch; branch-1 uses are done) ----
    float* t_loc = scratch;
    float* t_glb = t_loc + 58752;
    float* o_idn = t_glb + 58752;
    float* t3    = o_idn + 117504;
    float* o3    = t3 + 58752;
    float* o5    = o3 + 117504;
    float* t4    = o5 + 58752;
    float* o6    = t4 + 29376;
    float* o8    = o6 + 58752;
    float* t5    = o8 + 29376;
    float* o9    = t5 + 14400;
    float* o11   = o9 + 29376;

    float* s_tloc = stats + 810;
    float* s_tglb = s_tloc + 204;
    float* s_t3   = s_tglb + 204;
    float* s_o3   = s_t3 + 204;
    float* s_t4   = s_o3 + 408;
    float* s_o6   = s_t4 + 102;
    float* s_t5   = s_o6 + 204;
    float* s_o9   = s_t5 + 50;

    conv_dual<<<dim3(230, 1, 2), 256, 0, stream>>>(y, loc_w1, glb_w1, t_loc, t_glb,
                                                   s_tloc, s_tglb, 204, 102);
    crossatt_fused<<<459, 256, 0, stream>>>(y, t_loc, t_glb, s_tloc, s_tglb,
                                            loc_g, loc_b, glb_g, glb_b,
                                            loc_w2, glb_w2, o_idn);
    // c3
    conv1x1_k<<<230, 256, 0, stream>>>(o_idn, c3_w1, t3, s_t3, 204, 102, 9, 64, 0, 0, 0);
    invol3_fused<<<459, 256, 0, stream>>>(o_idn, t3, s_t3, c3_g, c3_b, c3_w2, o3, s_o3, 204, 102);
    bnconv<<<230, 256, 0, stream>>>(o3, s_o3, bn1g, bn1b, o_idn, p1, o5, 204, 102);
    // c4
    conv1x1_k<<<115, 256, 0, stream>>>(o5, c4_w1, t4, s_t4, 102, 51, 9, 64, 0, 0, 0);
    invol3_fused<<<230, 256, 0, stream>>>(o5, t4, s_t4, c4_g, c4_b, c4_w2, o6, s_o6, 102, 51);
    bnconv<<<115, 256, 0, stream>>>(o6, s_o6, bn2g, bn2b, nullptr, p2, o8, 102, 51);
    // c5
    conv1x1_k<<<57, 256, 0, stream>>>(o8, c5_w1, t5, s_t5, 51, 25, 9, 64, 0, 0, 0);
    invol3_fused<<<115, 256, 0, stream>>>(o8, t5, s_t5, c5_g, c5_b, c5_w2, o9, s_o9, 51, 25);
    bnconv<<<36, 256, 0, stream>>>(o9, s_o9, bn3g, bn3b, o8, p3, o11, 51, 16);
    covpool<16, 9, 256><<<64, 256, 0, stream>>>(o11, feat2);

    // ---- head ----
    head_k<<<1, 256, 0, stream>>>(feat1, feat2, hg, hb, lw, lb, (float*)d_out);
}